// Round 1
// baseline (236.272 us; speedup 1.0000x reference)
//
#include <hip/hip_runtime.h>
#include <math.h>

#define BD 8
#define NN 1000
#define GG 1000
#define EE 128

// ws layout (floats)
#define OFF_QG    0                       // B*128
#define OFF_K     1024                    // 8000*128
#define OFF_V     (OFF_K + 1024000)
#define OFF_QFL   (OFF_V + 1024000)
#define OFF_OUTG  (OFF_QFL + 1024000)
#define OFF_FQ    (OFF_OUTG + 1024000)
#define OFF_PART  (OFF_FQ + 1024000)      // 8000*16

// ---------------- K1: graph embedding mean + q_graph (B x 128) ----------------
__global__ __launch_bounds__(1024) void k_graphq(const float* __restrict__ emb,
                                                 const float* __restrict__ Wqg,
                                                 float* __restrict__ qg) {
  __shared__ float partial[8][128];
  __shared__ float ge[128];
  int b = blockIdx.x;
  int t = threadIdx.x;          // 1024 threads
  int e = t & 127, p = t >> 7;  // 8 slices of N
  const float* eb = emb + (size_t)b * NN * EE;
  float s = 0.f;
  int n0 = p * 125;
  for (int n = n0; n < n0 + 125; ++n) s += eb[(size_t)n * EE + e];
  partial[p][e] = s;
  __syncthreads();
  if (t < 128) {
    float m = 0.f;
#pragma unroll
    for (int q = 0; q < 8; ++q) m += partial[q][t];
    ge[t] = m * (1.f / 1000.f);
  }
  __syncthreads();
  if (t < 128) {
    const float* wr = Wqg + (size_t)t * EE;
    float acc = 0.f;
#pragma unroll 8
    for (int k = 0; k < 128; ++k) acc += ge[k] * wr[k];
    qg[b * EE + t] = acc;
  }
}

// ---------------- K2: fused projection GEMM  P = emb @ [Wk;Wv;Wqf+Wql]^T ----------------
// grid (125, 6), block 256. Tile 64x64, thread 4x4, K=128 in steps of 16.
__global__ __launch_bounds__(256) void k_proj(const float* __restrict__ emb,
                                              const float* __restrict__ Wk,
                                              const float* __restrict__ Wv,
                                              const float* __restrict__ Wqf,
                                              const float* __restrict__ Wql,
                                              float* __restrict__ Karr,
                                              float* __restrict__ Varr,
                                              float* __restrict__ QFL) {
  __shared__ float Als[16][68];
  __shared__ float Bls[16][68];
  int mt = blockIdx.x, nt = blockIdx.y;
  int t = threadIdx.x;
  int ty = t >> 4, tx = t & 15;
  int row4 = t >> 2, kq = t & 3;
  float acc[4][4] = {};
  for (int k0 = 0; k0 < 128; k0 += 16) {
    const float* ap = emb + (size_t)(mt * 64 + row4) * EE + k0 + kq * 4;
    float4 av = *(const float4*)ap;
    int j = nt * 64 + row4;
    float4 bv;
    if (j < 128) {
      bv = *(const float4*)(Wk + (size_t)j * EE + k0 + kq * 4);
    } else if (j < 256) {
      bv = *(const float4*)(Wv + (size_t)(j - 128) * EE + k0 + kq * 4);
    } else {
      float4 f = *(const float4*)(Wqf + (size_t)(j - 256) * EE + k0 + kq * 4);
      float4 l = *(const float4*)(Wql + (size_t)(j - 256) * EE + k0 + kq * 4);
      bv = make_float4(f.x + l.x, f.y + l.y, f.z + l.z, f.w + l.w);
    }
    Als[kq * 4 + 0][row4] = av.x; Als[kq * 4 + 1][row4] = av.y;
    Als[kq * 4 + 2][row4] = av.z; Als[kq * 4 + 3][row4] = av.w;
    Bls[kq * 4 + 0][row4] = bv.x; Bls[kq * 4 + 1][row4] = bv.y;
    Bls[kq * 4 + 2][row4] = bv.z; Bls[kq * 4 + 3][row4] = bv.w;
    __syncthreads();
#pragma unroll
    for (int k = 0; k < 16; ++k) {
      float a0 = Als[k][ty * 4 + 0], a1 = Als[k][ty * 4 + 1];
      float a2 = Als[k][ty * 4 + 2], a3 = Als[k][ty * 4 + 3];
      float b0 = Bls[k][tx * 4 + 0], b1 = Bls[k][tx * 4 + 1];
      float b2 = Bls[k][tx * 4 + 2], b3 = Bls[k][tx * 4 + 3];
      acc[0][0] += a0 * b0; acc[0][1] += a0 * b1; acc[0][2] += a0 * b2; acc[0][3] += a0 * b3;
      acc[1][0] += a1 * b0; acc[1][1] += a1 * b1; acc[1][2] += a1 * b2; acc[1][3] += a1 * b3;
      acc[2][0] += a2 * b0; acc[2][1] += a2 * b1; acc[2][2] += a2 * b2; acc[2][3] += a2 * b3;
      acc[3][0] += a3 * b0; acc[3][1] += a3 * b1; acc[3][2] += a3 * b2; acc[3][3] += a3 * b3;
    }
    __syncthreads();
  }
  float* outp; int cb;
  if (nt < 2)      { outp = Karr; cb = nt * 64; }
  else if (nt < 4) { outp = Varr; cb = (nt - 2) * 64; }
  else             { outp = QFL;  cb = (nt - 4) * 64; }
#pragma unroll
  for (int i = 0; i < 4; ++i) {
    int r = mt * 64 + ty * 4 + i;
    float4 v = make_float4(acc[i][0], acc[i][1], acc[i][2], acc[i][3]);
    *(float4*)(outp + (size_t)r * EE + cb + tx * 4) = v;
  }
}

// ---------------- K3: per-(b,g) KNN + glimpse attention -> outg (B,G,128) ----------------
// one wave per (b,g); grid 2000 x 256 (4 waves/block)
__global__ __launch_bounds__(256) void k_glimpse(const int* __restrict__ last_node,
                                                 const float* __restrict__ coords,
                                                 const float* __restrict__ mask,
                                                 const float* __restrict__ qg,
                                                 const float* __restrict__ QFL,
                                                 const float* __restrict__ Karr,
                                                 const float* __restrict__ Varr,
                                                 float* __restrict__ outg) {
  const float INF = __builtin_inff();
  int wid = (blockIdx.x * blockDim.x + threadIdx.x) >> 6;
  int lane = threadIdx.x & 63;
  int b = wid / GG, g = wid % GG;
  int last = last_node[b * GG + g];
  const float* cb = coords + (size_t)b * NN * 2;
  float lcx = cb[last * 2 + 0], lcy = cb[last * 2 + 1];
  float lc2 = lcx * lcx + lcy * lcy;
  const float* mrow = mask + ((size_t)b * GG + g) * NN;
  // per-lane squared distances, n = lane + 64*i
  float d2v[16];
#pragma unroll
  for (int i = 0; i < 16; ++i) {
    int n = lane + 64 * i;
    float v = INF;
    if (n < NN) {
      float cx = cb[n * 2 + 0], cy = cb[n * 2 + 1];
      float d2 = lc2 + (cx * cx + cy * cy) - 2.f * (lcx * cx + lcy * cy);
      if (mrow[n] == -INF) d2 = INF;
      v = d2;
    }
    d2v[i] = v;
  }
  // 16 rounds of wave argmin on (d2, n); ties -> smaller n (matches lax.top_k)
  int h = lane >> 3;   // head 0..7
  int kk = lane & 7;   // this lane scores k=kk and k=kk+8
  int n0sel = 0, n1sel = 0;
#pragma unroll
  for (int s = 0; s < 16; ++s) {
    float bestv = d2v[0]; int bestn = lane;
#pragma unroll
    for (int i = 1; i < 16; ++i) {
      int n = lane + 64 * i;
      float v = d2v[i];
      if (v < bestv) { bestv = v; bestn = n; }  // same-lane ties keep smaller n
    }
#pragma unroll
    for (int off = 1; off < 64; off <<= 1) {
      float ov = __shfl_xor(bestv, off);
      int on = __shfl_xor(bestn, off);
      if (ov < bestv || (ov == bestv && on < bestn)) { bestv = ov; bestn = on; }
    }
    if (s == kk) n0sel = bestn;
    if (s == kk + 8) n1sel = bestn;
#pragma unroll
    for (int i = 0; i < 16; ++i)
      if (lane + 64 * i == bestn) d2v[i] = INF;
  }
  // glimpse q for this lane's head
  float qh[16];
  const float* qfl = QFL + ((size_t)b * GG + last) * EE + h * 16;
  const float* qgb = qg + b * EE + h * 16;
#pragma unroll
  for (int d = 0; d < 16; ++d) qh[d] = qgb[d] + qfl[d];
  // scores for (h, kk) and (h, kk+8)
  const float* Kb = Karr + (size_t)b * NN * EE;
  const float* k0p = Kb + (size_t)n0sel * EE + h * 16;
  const float* k1p = Kb + (size_t)n1sel * EE + h * 16;
  float s0 = 0.f, s1 = 0.f;
#pragma unroll
  for (int d = 0; d < 16; ++d) { s0 += qh[d] * k0p[d]; s1 += qh[d] * k1p[d]; }
  s0 *= 0.25f; s1 *= 0.25f;  // 1/sqrt(16)
  // softmax over the 16 scores of head h (held 2-per-lane across the 8-lane group)
  float m = fmaxf(s0, s1);
#pragma unroll
  for (int off = 1; off < 8; off <<= 1) m = fmaxf(m, __shfl_xor(m, off));
  float e0 = expf(s0 - m), e1 = expf(s1 - m);
  float se = e0 + e1;
#pragma unroll
  for (int off = 1; off < 8; off <<= 1) se += __shfl_xor(se, off);
  float p0 = e0 / se, p1 = e1 / se;
  // out dims for this lane: e = 2*lane, 2*lane+1 (== h*16 + kk*2 + {0,1})
  const float* Vb = Varr + (size_t)b * NN * EE;
  float o0 = 0.f, o1 = 0.f;
#pragma unroll
  for (int k = 0; k < 16; ++k) {
    int src = h * 8 + (k & 7);
    float pk = (k < 8) ? __shfl(p0, src) : __shfl(p1, src);
    int nk = (k < 8) ? __shfl(n0sel, src) : __shfl(n1sel, src);
    const float* vp = Vb + (size_t)nk * EE + h * 16 + kk * 2;
    o0 += pk * vp[0]; o1 += pk * vp[1];
  }
  float* op = outg + ((size_t)b * GG + g) * EE + lane * 2;
  op[0] = o0; op[1] = o1;
}

// ---------------- K4: final_q = outg @ W_comb^T + b_comb ----------------
// grid (125, 2), block 256
__global__ __launch_bounds__(256) void k_comb(const float* __restrict__ outg,
                                              const float* __restrict__ Wc,
                                              const float* __restrict__ bc,
                                              float* __restrict__ fq) {
  __shared__ float Als[16][68];
  __shared__ float Bls[16][68];
  int mt = blockIdx.x, nt = blockIdx.y;
  int t = threadIdx.x;
  int ty = t >> 4, tx = t & 15;
  int row4 = t >> 2, kq = t & 3;
  float acc[4][4] = {};
  for (int k0 = 0; k0 < 128; k0 += 16) {
    float4 av = *(const float4*)(outg + (size_t)(mt * 64 + row4) * EE + k0 + kq * 4);
    int j = nt * 64 + row4;
    float4 bv = *(const float4*)(Wc + (size_t)j * EE + k0 + kq * 4);
    Als[kq * 4 + 0][row4] = av.x; Als[kq * 4 + 1][row4] = av.y;
    Als[kq * 4 + 2][row4] = av.z; Als[kq * 4 + 3][row4] = av.w;
    Bls[kq * 4 + 0][row4] = bv.x; Bls[kq * 4 + 1][row4] = bv.y;
    Bls[kq * 4 + 2][row4] = bv.z; Bls[kq * 4 + 3][row4] = bv.w;
    __syncthreads();
#pragma unroll
    for (int k = 0; k < 16; ++k) {
      float a0 = Als[k][ty * 4 + 0], a1 = Als[k][ty * 4 + 1];
      float a2 = Als[k][ty * 4 + 2], a3 = Als[k][ty * 4 + 3];
      float b0 = Bls[k][tx * 4 + 0], b1 = Bls[k][tx * 4 + 1];
      float b2 = Bls[k][tx * 4 + 2], b3 = Bls[k][tx * 4 + 3];
      acc[0][0] += a0 * b0; acc[0][1] += a0 * b1; acc[0][2] += a0 * b2; acc[0][3] += a0 * b3;
      acc[1][0] += a1 * b0; acc[1][1] += a1 * b1; acc[1][2] += a1 * b2; acc[1][3] += a1 * b3;
      acc[2][0] += a2 * b0; acc[2][1] += a2 * b1; acc[2][2] += a2 * b2; acc[2][3] += a2 * b3;
      acc[3][0] += a3 * b0; acc[3][1] += a3 * b1; acc[3][2] += a3 * b2; acc[3][3] += a3 * b3;
    }
    __syncthreads();
  }
#pragma unroll
  for (int i = 0; i < 4; ++i) {
    int r = mt * 64 + ty * 4 + i;
    int c = nt * 64 + tx * 4;
    float4 v = make_float4(acc[i][0] + bc[c + 0], acc[i][1] + bc[c + 1],
                           acc[i][2] + bc[c + 2], acc[i][3] + bc[c + 3]);
    *(float4*)(fq + (size_t)r * EE + c) = v;
  }
}

// ---------------- K5: score GEMM + tanh clip + exp (no max needed) + partial sums ----------
// grid (8, 16, 16): b, g-tile(64), n-tile(64). block 256, thread 4x4.
__global__ __launch_bounds__(256) void k_score(const float* __restrict__ fq,
                                               const float* __restrict__ emb,
                                               const float* __restrict__ mask,
                                               float* __restrict__ out,
                                               float* __restrict__ part) {
  __shared__ float Als[16][68];
  __shared__ float Bls[16][68];
  int b = blockIdx.x, gt = blockIdx.y, nt = blockIdx.z;
  int t = threadIdx.x;
  int ty = t >> 4, tx = t & 15;
  int row4 = t >> 2, kq = t & 3;
  int g0 = gt * 64, n0 = nt * 64;
  const float* A = fq + (size_t)b * GG * EE;
  const float* Bm = emb + (size_t)b * NN * EE;
  float acc[4][4] = {};
  for (int k0 = 0; k0 < 128; k0 += 16) {
    int gr = g0 + row4, nr = n0 + row4;
    float4 av = make_float4(0.f, 0.f, 0.f, 0.f), bv = av;
    if (gr < GG) av = *(const float4*)(A + (size_t)gr * EE + k0 + kq * 4);
    if (nr < NN) bv = *(const float4*)(Bm + (size_t)nr * EE + k0 + kq * 4);
    Als[kq * 4 + 0][row4] = av.x; Als[kq * 4 + 1][row4] = av.y;
    Als[kq * 4 + 2][row4] = av.z; Als[kq * 4 + 3][row4] = av.w;
    Bls[kq * 4 + 0][row4] = bv.x; Bls[kq * 4 + 1][row4] = bv.y;
    Bls[kq * 4 + 2][row4] = bv.z; Bls[kq * 4 + 3][row4] = bv.w;
    __syncthreads();
#pragma unroll
    for (int k = 0; k < 16; ++k) {
      float a0 = Als[k][ty * 4 + 0], a1 = Als[k][ty * 4 + 1];
      float a2 = Als[k][ty * 4 + 2], a3 = Als[k][ty * 4 + 3];
      float b0 = Bls[k][tx * 4 + 0], b1 = Bls[k][tx * 4 + 1];
      float b2 = Bls[k][tx * 4 + 2], b3 = Bls[k][tx * 4 + 3];
      acc[0][0] += a0 * b0; acc[0][1] += a0 * b1; acc[0][2] += a0 * b2; acc[0][3] += a0 * b3;
      acc[1][0] += a1 * b0; acc[1][1] += a1 * b1; acc[1][2] += a1 * b2; acc[1][3] += a1 * b3;
      acc[2][0] += a2 * b0; acc[2][1] += a2 * b1; acc[2][2] += a2 * b2; acc[2][3] += a2 * b3;
      acc[3][0] += a3 * b0; acc[3][1] += a3 * b1; acc[3][2] += a3 * b2; acc[3][3] += a3 * b3;
    }
    __syncthreads();
  }
  const float rs = 0.08838834764831845f;  // 1/sqrt(128)
#pragma unroll
  for (int i = 0; i < 4; ++i) {
    int g = g0 + ty * 4 + i;
    bool gv = (g < GG);
    const float* mrow = mask + ((size_t)b * GG + g) * NN;
    float* orow = out + ((size_t)b * GG + g) * NN;
    float rsacc = 0.f;
#pragma unroll
    for (int j = 0; j < 4; ++j) {
      int n = n0 + tx * 4 + j;
      float e = 0.f;
      if (gv && n < NN) {
        float sc = acc[i][j] * rs;
        float sm = 10.f * tanhf(sc) + mrow[n];
        e = expf(sm);           // safe: |10*tanh| <= 10
        orow[n] = e;
      }
      rsacc += e;
    }
#pragma unroll
    for (int off = 1; off < 16; off <<= 1) rsacc += __shfl_xor(rsacc, off);
    if (tx == 0 && gv) part[((size_t)b * GG + g) * 16 + nt] = rsacc;
  }
}

// ---------------- K6: normalize: probs = exp / rowsum ----------------
// grid 8000 (one block per (b,g) row), block 256
__global__ __launch_bounds__(256) void k_norm(const float* __restrict__ part,
                                              float* __restrict__ out) {
  int row = blockIdx.x;
  __shared__ float ssum;
  int t = threadIdx.x;
  float v = (t < 16) ? part[(size_t)row * 16 + t] : 0.f;
#pragma unroll
  for (int off = 1; off < 16; off <<= 1) v += __shfl_xor(v, off);
  if (t == 0) ssum = v;
  __syncthreads();
  float inv = 1.f / ssum;
  if (t < 250) {
    float4* o = (float4*)(out + (size_t)row * NN);
    float4 x = o[t];
    x.x *= inv; x.y *= inv; x.z *= inv; x.w *= inv;
    o[t] = x;
  }
}

extern "C" void kernel_launch(void* const* d_in, const int* in_sizes, int n_in,
                              void* d_out, int out_size, void* d_ws, size_t ws_size,
                              hipStream_t stream) {
  const int*   last_node = (const int*)d_in[0];
  const float* coords    = (const float*)d_in[1];
  const float* emb       = (const float*)d_in[2];
  const float* mask      = (const float*)d_in[3];
  const float* Wqg       = (const float*)d_in[4];
  const float* Wqf       = (const float*)d_in[5];
  const float* Wql       = (const float*)d_in[6];
  const float* Wk        = (const float*)d_in[7];
  const float* Wv        = (const float*)d_in[8];
  const float* Wc        = (const float*)d_in[9];
  const float* bc        = (const float*)d_in[10];
  float* out = (float*)d_out;
  float* ws  = (float*)d_ws;

  float* qg   = ws + OFF_QG;
  float* Karr = ws + OFF_K;
  float* Varr = ws + OFF_V;
  float* QFL  = ws + OFF_QFL;
  float* outg = ws + OFF_OUTG;
  float* fq   = ws + OFF_FQ;
  float* part = ws + OFF_PART;

  k_graphq<<<dim3(BD), dim3(1024), 0, stream>>>(emb, Wqg, qg);
  k_proj<<<dim3(125, 6), dim3(256), 0, stream>>>(emb, Wk, Wv, Wqf, Wql, Karr, Varr, QFL);
  k_glimpse<<<dim3(2000), dim3(256), 0, stream>>>(last_node, coords, mask, qg, QFL, Karr, Varr, outg);
  k_comb<<<dim3(125, 2), dim3(256), 0, stream>>>(outg, Wc, bc, fq);
  k_score<<<dim3(8, 16, 16), dim3(256), 0, stream>>>(fq, emb, mask, out, part);
  k_norm<<<dim3(8000), dim3(256), 0, stream>>>(part, out);
}

// Round 2
// 227.853 us; speedup vs baseline: 1.0370x; 1.0370x over previous
//
#include <hip/hip_runtime.h>
#include <math.h>

#define BD 8
#define NN 1000
#define GG 1000
#define EE 128

// ws layout (floats)
#define OFF_QG    0                       // B*128
#define OFF_K     1024                    // 8000*128
#define OFF_V     (OFF_K + 1024000)
#define OFF_QFL   (OFF_V + 1024000)
#define OFF_OUTG  (OFF_QFL + 1024000)
#define OFF_FQ    (OFF_OUTG + 1024000)
#define OFF_PART  (OFF_FQ + 1024000)      // 8000*8

// ---------------- K1: graph embedding mean + q_graph (B x 128) ----------------
__global__ __launch_bounds__(1024) void k_graphq(const float* __restrict__ emb,
                                                 const float* __restrict__ Wqg,
                                                 float* __restrict__ qg) {
  __shared__ float partial[8][128];
  __shared__ float ge[128];
  int b = blockIdx.x;
  int t = threadIdx.x;          // 1024 threads
  int e = t & 127, p = t >> 7;  // 8 slices of N
  const float* eb = emb + (size_t)b * NN * EE;
  float s = 0.f;
  int n0 = p * 125;
  for (int n = n0; n < n0 + 125; ++n) s += eb[(size_t)n * EE + e];
  partial[p][e] = s;
  __syncthreads();
  if (t < 128) {
    float m = 0.f;
#pragma unroll
    for (int q = 0; q < 8; ++q) m += partial[q][t];
    ge[t] = m * (1.f / 1000.f);
  }
  __syncthreads();
  if (t < 128) {
    const float* wr = Wqg + (size_t)t * EE;
    float acc = 0.f;
#pragma unroll 8
    for (int k = 0; k < 128; ++k) acc += ge[k] * wr[k];
    qg[b * EE + t] = acc;
  }
}

// ---------------- K2: fused projection GEMM  P = emb @ [Wk;Wv;Wqf+Wql]^T ----------------
// grid (125, 6), block 256. Tile 64x64, thread 4x4, K=128 in steps of 16.
__global__ __launch_bounds__(256) void k_proj(const float* __restrict__ emb,
                                              const float* __restrict__ Wk,
                                              const float* __restrict__ Wv,
                                              const float* __restrict__ Wqf,
                                              const float* __restrict__ Wql,
                                              float* __restrict__ Karr,
                                              float* __restrict__ Varr,
                                              float* __restrict__ QFL) {
  __shared__ float Als[16][68];
  __shared__ float Bls[16][68];
  int mt = blockIdx.x, nt = blockIdx.y;
  int t = threadIdx.x;
  int ty = t >> 4, tx = t & 15;
  int row4 = t >> 2, kq = t & 3;
  float acc[4][4] = {};
  for (int k0 = 0; k0 < 128; k0 += 16) {
    const float* ap = emb + (size_t)(mt * 64 + row4) * EE + k0 + kq * 4;
    float4 av = *(const float4*)ap;
    int j = nt * 64 + row4;
    float4 bv;
    if (j < 128) {
      bv = *(const float4*)(Wk + (size_t)j * EE + k0 + kq * 4);
    } else if (j < 256) {
      bv = *(const float4*)(Wv + (size_t)(j - 128) * EE + k0 + kq * 4);
    } else {
      float4 f = *(const float4*)(Wqf + (size_t)(j - 256) * EE + k0 + kq * 4);
      float4 l = *(const float4*)(Wql + (size_t)(j - 256) * EE + k0 + kq * 4);
      bv = make_float4(f.x + l.x, f.y + l.y, f.z + l.z, f.w + l.w);
    }
    Als[kq * 4 + 0][row4] = av.x; Als[kq * 4 + 1][row4] = av.y;
    Als[kq * 4 + 2][row4] = av.z; Als[kq * 4 + 3][row4] = av.w;
    Bls[kq * 4 + 0][row4] = bv.x; Bls[kq * 4 + 1][row4] = bv.y;
    Bls[kq * 4 + 2][row4] = bv.z; Bls[kq * 4 + 3][row4] = bv.w;
    __syncthreads();
#pragma unroll
    for (int k = 0; k < 16; ++k) {
      float a0 = Als[k][ty * 4 + 0], a1 = Als[k][ty * 4 + 1];
      float a2 = Als[k][ty * 4 + 2], a3 = Als[k][ty * 4 + 3];
      float b0 = Bls[k][tx * 4 + 0], b1 = Bls[k][tx * 4 + 1];
      float b2 = Bls[k][tx * 4 + 2], b3 = Bls[k][tx * 4 + 3];
      acc[0][0] += a0 * b0; acc[0][1] += a0 * b1; acc[0][2] += a0 * b2; acc[0][3] += a0 * b3;
      acc[1][0] += a1 * b0; acc[1][1] += a1 * b1; acc[1][2] += a1 * b2; acc[1][3] += a1 * b3;
      acc[2][0] += a2 * b0; acc[2][1] += a2 * b1; acc[2][2] += a2 * b2; acc[2][3] += a2 * b3;
      acc[3][0] += a3 * b0; acc[3][1] += a3 * b1; acc[3][2] += a3 * b2; acc[3][3] += a3 * b3;
    }
    __syncthreads();
  }
  float* outp; int cb;
  if (nt < 2)      { outp = Karr; cb = nt * 64; }
  else if (nt < 4) { outp = Varr; cb = (nt - 2) * 64; }
  else             { outp = QFL;  cb = (nt - 4) * 64; }
#pragma unroll
  for (int i = 0; i < 4; ++i) {
    int r = mt * 64 + ty * 4 + i;
    float4 v = make_float4(acc[i][0], acc[i][1], acc[i][2], acc[i][3]);
    *(float4*)(outp + (size_t)r * EE + cb + tx * 4) = v;
  }
}

// ---------------- K3: per-(b,g) KNN + glimpse attention -> outg (B,G,128) ----------------
// one wave per (b,g); grid 2000 x 256 (4 waves/block)
__global__ __launch_bounds__(256) void k_glimpse(const int* __restrict__ last_node,
                                                 const float* __restrict__ coords,
                                                 const float* __restrict__ mask,
                                                 const float* __restrict__ qg,
                                                 const float* __restrict__ QFL,
                                                 const float* __restrict__ Karr,
                                                 const float* __restrict__ Varr,
                                                 float* __restrict__ outg) {
  const float INF = __builtin_inff();
  int wid = (blockIdx.x * blockDim.x + threadIdx.x) >> 6;
  int lane = threadIdx.x & 63;
  int b = wid / GG, g = wid % GG;
  int last = last_node[b * GG + g];
  const float* cb = coords + (size_t)b * NN * 2;
  float lcx = cb[last * 2 + 0], lcy = cb[last * 2 + 1];
  float lc2 = lcx * lcx + lcy * lcy;
  const float* mrow = mask + ((size_t)b * GG + g) * NN;
  // per-lane squared distances, n = lane + 64*i
  float d2v[16];
#pragma unroll
  for (int i = 0; i < 16; ++i) {
    int n = lane + 64 * i;
    float v = INF;
    if (n < NN) {
      float cx = cb[n * 2 + 0], cy = cb[n * 2 + 1];
      float d2 = lc2 + (cx * cx + cy * cy) - 2.f * (lcx * cx + lcy * cy);
      d2 = fmaxf(d2, 0.f);  // match reference sqrt(max(d2,0)) tie semantics
      if (mrow[n] == -INF) d2 = INF;
      v = d2;
    }
    d2v[i] = v;
  }
  // 16 rounds of wave argmin on (d2, n); ties -> smaller n (matches lax.top_k)
  int h = lane >> 3;   // head 0..7
  int kk = lane & 7;   // this lane scores k=kk and k=kk+8
  int n0sel = 0, n1sel = 0;
#pragma unroll
  for (int s = 0; s < 16; ++s) {
    float bestv = d2v[0]; int bestn = lane;
#pragma unroll
    for (int i = 1; i < 16; ++i) {
      int n = lane + 64 * i;
      float v = d2v[i];
      if (v < bestv) { bestv = v; bestn = n; }  // same-lane ties keep smaller n
    }
#pragma unroll
    for (int off = 1; off < 64; off <<= 1) {
      float ov = __shfl_xor(bestv, off);
      int on = __shfl_xor(bestn, off);
      if (ov < bestv || (ov == bestv && on < bestn)) { bestv = ov; bestn = on; }
    }
    if (s == kk) n0sel = bestn;
    if (s == kk + 8) n1sel = bestn;
#pragma unroll
    for (int i = 0; i < 16; ++i)
      if (lane + 64 * i == bestn) d2v[i] = INF;
  }
  // glimpse q for this lane's head
  float qh[16];
  const float* qfl = QFL + ((size_t)b * GG + last) * EE + h * 16;
  const float* qgb = qg + b * EE + h * 16;
#pragma unroll
  for (int d = 0; d < 16; ++d) qh[d] = qgb[d] + qfl[d];
  // scores for (h, kk) and (h, kk+8)
  const float* Kb = Karr + (size_t)b * NN * EE;
  const float* k0p = Kb + (size_t)n0sel * EE + h * 16;
  const float* k1p = Kb + (size_t)n1sel * EE + h * 16;
  float s0 = 0.f, s1 = 0.f;
#pragma unroll
  for (int d = 0; d < 16; ++d) { s0 += qh[d] * k0p[d]; s1 += qh[d] * k1p[d]; }
  s0 *= 0.25f; s1 *= 0.25f;  // 1/sqrt(16)
  // softmax over the 16 scores of head h (held 2-per-lane across the 8-lane group)
  float m = fmaxf(s0, s1);
#pragma unroll
  for (int off = 1; off < 8; off <<= 1) m = fmaxf(m, __shfl_xor(m, off));
  float e0 = expf(s0 - m), e1 = expf(s1 - m);
  float se = e0 + e1;
#pragma unroll
  for (int off = 1; off < 8; off <<= 1) se += __shfl_xor(se, off);
  float p0 = e0 / se, p1 = e1 / se;
  // out dims for this lane: e = 2*lane, 2*lane+1 (== h*16 + kk*2 + {0,1})
  const float* Vb = Varr + (size_t)b * NN * EE;
  float o0 = 0.f, o1 = 0.f;
#pragma unroll
  for (int k = 0; k < 16; ++k) {
    int src = h * 8 + (k & 7);
    float pk = (k < 8) ? __shfl(p0, src) : __shfl(p1, src);
    int nk = (k < 8) ? __shfl(n0sel, src) : __shfl(n1sel, src);
    const float* vp = Vb + (size_t)nk * EE + h * 16 + kk * 2;
    o0 += pk * vp[0]; o1 += pk * vp[1];
  }
  float* op = outg + ((size_t)b * GG + g) * EE + lane * 2;
  op[0] = o0; op[1] = o1;
}

// ---------------- K4: final_q = outg @ W_comb^T + b_comb ----------------
// grid (125, 2), block 256
__global__ __launch_bounds__(256) void k_comb(const float* __restrict__ outg,
                                              const float* __restrict__ Wc,
                                              const float* __restrict__ bc,
                                              float* __restrict__ fq) {
  __shared__ float Als[16][68];
  __shared__ float Bls[16][68];
  int mt = blockIdx.x, nt = blockIdx.y;
  int t = threadIdx.x;
  int ty = t >> 4, tx = t & 15;
  int row4 = t >> 2, kq = t & 3;
  float acc[4][4] = {};
  for (int k0 = 0; k0 < 128; k0 += 16) {
    float4 av = *(const float4*)(outg + (size_t)(mt * 64 + row4) * EE + k0 + kq * 4);
    int j = nt * 64 + row4;
    float4 bv = *(const float4*)(Wc + (size_t)j * EE + k0 + kq * 4);
    Als[kq * 4 + 0][row4] = av.x; Als[kq * 4 + 1][row4] = av.y;
    Als[kq * 4 + 2][row4] = av.z; Als[kq * 4 + 3][row4] = av.w;
    Bls[kq * 4 + 0][row4] = bv.x; Bls[kq * 4 + 1][row4] = bv.y;
    Bls[kq * 4 + 2][row4] = bv.z; Bls[kq * 4 + 3][row4] = bv.w;
    __syncthreads();
#pragma unroll
    for (int k = 0; k < 16; ++k) {
      float a0 = Als[k][ty * 4 + 0], a1 = Als[k][ty * 4 + 1];
      float a2 = Als[k][ty * 4 + 2], a3 = Als[k][ty * 4 + 3];
      float b0 = Bls[k][tx * 4 + 0], b1 = Bls[k][tx * 4 + 1];
      float b2 = Bls[k][tx * 4 + 2], b3 = Bls[k][tx * 4 + 3];
      acc[0][0] += a0 * b0; acc[0][1] += a0 * b1; acc[0][2] += a0 * b2; acc[0][3] += a0 * b3;
      acc[1][0] += a1 * b0; acc[1][1] += a1 * b1; acc[1][2] += a1 * b2; acc[1][3] += a1 * b3;
      acc[2][0] += a2 * b0; acc[2][1] += a2 * b1; acc[2][2] += a2 * b2; acc[2][3] += a2 * b3;
      acc[3][0] += a3 * b0; acc[3][1] += a3 * b1; acc[3][2] += a3 * b2; acc[3][3] += a3 * b3;
    }
    __syncthreads();
  }
#pragma unroll
  for (int i = 0; i < 4; ++i) {
    int r = mt * 64 + ty * 4 + i;
    int c = nt * 64 + tx * 4;
    float4 v = make_float4(acc[i][0] + bc[c + 0], acc[i][1] + bc[c + 1],
                           acc[i][2] + bc[c + 2], acc[i][3] + bc[c + 3]);
    *(float4*)(fq + (size_t)r * EE + c) = v;
  }
}

// ---------------- K5: score GEMM 128x128 tile + tanh clip + exp + partial sums ----------
// grid (8, 8, 8): b, g-tile(128), n-tile(128). block 256, thread 8x8.
// exp needs no max-subtraction: logits in [-10,10] (+ -inf mask) -> overflow-safe.
__global__ __launch_bounds__(256, 2) void k_score(const float* __restrict__ fq,
                                                  const float* __restrict__ emb,
                                                  const float* __restrict__ mask,
                                                  float* __restrict__ out,
                                                  float* __restrict__ part) {
  __shared__ float As[16][132];   // row stride 528B: 16B-aligned, float4-readable
  __shared__ float Bs[16][132];
  int b = blockIdx.x, gt = blockIdx.y, nt = blockIdx.z;
  int t = threadIdx.x;
  int tx = t & 15, ty = t >> 4;
  int g0 = gt * 128, n0 = nt * 128;
  const float* A = fq + (size_t)b * GG * EE;
  const float* Bm = emb + (size_t)b * NN * EE;
  int lr = t >> 1;          // staging row 0..127
  int lq = t & 1;           // which 8-float half of the 16-wide k slab
  int ar = min(g0 + lr, GG - 1);
  int br = min(n0 + lr, NN - 1);
  const float* apos = A + (size_t)ar * EE + lq * 8;
  const float* bpos = Bm + (size_t)br * EE + lq * 8;

  float acc[8][8] = {};
  // prefetch k0 = 0
  float4 sa0 = *(const float4*)(apos + 0);
  float4 sa1 = *(const float4*)(apos + 4);
  float4 sb0 = *(const float4*)(bpos + 0);
  float4 sb1 = *(const float4*)(bpos + 4);
  for (int k0 = 0; k0 < 128; k0 += 16) {
    __syncthreads();  // previous compute done reading LDS
    As[lq * 8 + 0][lr] = sa0.x; As[lq * 8 + 1][lr] = sa0.y;
    As[lq * 8 + 2][lr] = sa0.z; As[lq * 8 + 3][lr] = sa0.w;
    As[lq * 8 + 4][lr] = sa1.x; As[lq * 8 + 5][lr] = sa1.y;
    As[lq * 8 + 6][lr] = sa1.z; As[lq * 8 + 7][lr] = sa1.w;
    Bs[lq * 8 + 0][lr] = sb0.x; Bs[lq * 8 + 1][lr] = sb0.y;
    Bs[lq * 8 + 2][lr] = sb0.z; Bs[lq * 8 + 3][lr] = sb0.w;
    Bs[lq * 8 + 4][lr] = sb1.x; Bs[lq * 8 + 5][lr] = sb1.y;
    Bs[lq * 8 + 6][lr] = sb1.z; Bs[lq * 8 + 7][lr] = sb1.w;
    __syncthreads();
    if (k0 < 112) {  // prefetch next slab (overlaps with compute below)
      sa0 = *(const float4*)(apos + k0 + 16);
      sa1 = *(const float4*)(apos + k0 + 20);
      sb0 = *(const float4*)(bpos + k0 + 16);
      sb1 = *(const float4*)(bpos + k0 + 20);
    }
#pragma unroll
    for (int k = 0; k < 16; ++k) {
      float4 av0 = *(const float4*)&As[k][ty * 8];
      float4 av1 = *(const float4*)&As[k][ty * 8 + 4];
      float4 bv0 = *(const float4*)&Bs[k][tx * 8];
      float4 bv1 = *(const float4*)&Bs[k][tx * 8 + 4];
      float af[8] = {av0.x, av0.y, av0.z, av0.w, av1.x, av1.y, av1.z, av1.w};
      float bf[8] = {bv0.x, bv0.y, bv0.z, bv0.w, bv1.x, bv1.y, bv1.z, bv1.w};
#pragma unroll
      for (int i = 0; i < 8; ++i)
#pragma unroll
        for (int j = 0; j < 8; ++j) acc[i][j] += af[i] * bf[j];
    }
  }

  const float rs = 0.08838834764831845f;  // 1/sqrt(128)
  const float NEGINF = -__builtin_inff();
  int gbase = g0 + ty * 8;
  int nb = n0 + tx * 8;
  bool nfull = (nb + 7 < NN);
#pragma unroll
  for (int i = 0; i < 8; ++i) {
    int g = gbase + i;
    int gc = g < GG ? g : GG - 1;
    const float* mrow = mask + ((size_t)b * GG + gc) * NN;
    float* orow = out + ((size_t)b * GG + gc) * NN;
    float mv[8];
    if (nfull) {
      float4 m0 = *(const float4*)(mrow + nb);
      float4 m1 = *(const float4*)(mrow + nb + 4);
      mv[0] = m0.x; mv[1] = m0.y; mv[2] = m0.z; mv[3] = m0.w;
      mv[4] = m1.x; mv[5] = m1.y; mv[6] = m1.z; mv[7] = m1.w;
    } else {
#pragma unroll
      for (int j = 0; j < 8; ++j) mv[j] = (nb + j < NN) ? mrow[nb + j] : NEGINF;
    }
    float e[8];
    float rsum = 0.f;
#pragma unroll
    for (int j = 0; j < 8; ++j) {
      float sc = acc[i][j] * rs;
      float u = __expf(2.f * sc);                          // e^{2sc}; inf-safe
      float th = 1.f - 2.f * __builtin_amdgcn_rcpf(u + 1.f);  // tanh(sc)
      float ev = __expf(10.f * th + mv[j]);                // mask -inf -> 0
      e[j] = ev;
      rsum += ev;   // OOB j contributes 0 (mv=-inf)
    }
    if (g < GG) {
      if (nfull) {
        *(float4*)(orow + nb)     = make_float4(e[0], e[1], e[2], e[3]);
        *(float4*)(orow + nb + 4) = make_float4(e[4], e[5], e[6], e[7]);
      } else {
#pragma unroll
        for (int j = 0; j < 8; ++j)
          if (nb + j < NN) orow[nb + j] = e[j];
      }
    }
#pragma unroll
    for (int off = 1; off < 16; off <<= 1) rsum += __shfl_xor(rsum, off);
    if (tx == 0 && g < GG) part[((size_t)b * GG + g) * 8 + nt] = rsum;
  }
}

// ---------------- K6: normalize: probs = exp / rowsum ----------------
// grid 8000 (one block per (b,g) row), block 256
__global__ __launch_bounds__(256) void k_norm(const float* __restrict__ part,
                                              float* __restrict__ out) {
  int row = blockIdx.x;
  __shared__ float ssum;
  int t = threadIdx.x;
  float v = (t < 8) ? part[(size_t)row * 8 + t] : 0.f;
#pragma unroll
  for (int off = 1; off < 8; off <<= 1) v += __shfl_xor(v, off);
  if (t == 0) ssum = v;
  __syncthreads();
  float inv = 1.f / ssum;
  if (t < 250) {
    float4* o = (float4*)(out + (size_t)row * NN);
    float4 x = o[t];
    x.x *= inv; x.y *= inv; x.z *= inv; x.w *= inv;
    o[t] = x;
  }
}

extern "C" void kernel_launch(void* const* d_in, const int* in_sizes, int n_in,
                              void* d_out, int out_size, void* d_ws, size_t ws_size,
                              hipStream_t stream) {
  const int*   last_node = (const int*)d_in[0];
  const float* coords    = (const float*)d_in[1];
  const float* emb       = (const float*)d_in[2];
  const float* mask      = (const float*)d_in[3];
  const float* Wqg       = (const float*)d_in[4];
  const float* Wqf       = (const float*)d_in[5];
  const float* Wql       = (const float*)d_in[6];
  const float* Wk        = (const float*)d_in[7];
  const float* Wv        = (const float*)d_in[8];
  const float* Wc        = (const float*)d_in[9];
  const float* bc        = (const float*)d_in[10];
  float* out = (float*)d_out;
  float* ws  = (float*)d_ws;

  float* qg   = ws + OFF_QG;
  float* Karr = ws + OFF_K;
  float* Varr = ws + OFF_V;
  float* QFL  = ws + OFF_QFL;
  float* outg = ws + OFF_OUTG;
  float* fq   = ws + OFF_FQ;
  float* part = ws + OFF_PART;

  k_graphq<<<dim3(BD), dim3(1024), 0, stream>>>(emb, Wqg, qg);
  k_proj<<<dim3(125, 6), dim3(256), 0, stream>>>(emb, Wk, Wv, Wqf, Wql, Karr, Varr, QFL);
  k_glimpse<<<dim3(2000), dim3(256), 0, stream>>>(last_node, coords, mask, qg, QFL, Karr, Varr, outg);
  k_comb<<<dim3(125, 2), dim3(256), 0, stream>>>(outg, Wc, bc, fq);
  k_score<<<dim3(8, 8, 8), dim3(256), 0, stream>>>(fq, emb, mask, out, part);
  k_norm<<<dim3(8000), dim3(256), 0, stream>>>(part, out);
}

// Round 4
// 224.995 us; speedup vs baseline: 1.0501x; 1.0127x over previous
//
#include <hip/hip_runtime.h>
#include <math.h>

#define BD 8
#define NN 1000
#define GG 1000
#define EE 128

// ws layout (floats)
#define OFF_QG    0                       // B*128
#define OFF_K     1024                    // 8000*128
#define OFF_V     (OFF_K + 1024000)
#define OFF_QFL   (OFF_V + 1024000)
#define OFF_OUTG  (OFF_QFL + 1024000)
#define OFF_FQ    (OFF_OUTG + 1024000)
#define OFF_PART  (OFF_FQ + 1024000)      // 8000*8

// ---------------- K1: graph embedding mean + q_graph (B x 128) ----------------
__global__ __launch_bounds__(1024) void k_graphq(const float* __restrict__ emb,
                                                 const float* __restrict__ Wqg,
                                                 float* __restrict__ qg) {
  __shared__ float partial[8][128];
  __shared__ float ge[128];
  int b = blockIdx.x;
  int t = threadIdx.x;          // 1024 threads
  int e = t & 127, p = t >> 7;  // 8 slices of N
  const float* eb = emb + (size_t)b * NN * EE;
  float s = 0.f;
  int n0 = p * 125;
  for (int n = n0; n < n0 + 125; ++n) s += eb[(size_t)n * EE + e];
  partial[p][e] = s;
  __syncthreads();
  if (t < 128) {
    float m = 0.f;
#pragma unroll
    for (int q = 0; q < 8; ++q) m += partial[q][t];
    ge[t] = m * (1.f / 1000.f);
  }
  __syncthreads();
  if (t < 128) {
    const float* wr = Wqg + (size_t)t * EE;
    float acc = 0.f;
#pragma unroll 8
    for (int k = 0; k < 128; ++k) acc += ge[k] * wr[k];
    qg[b * EE + t] = acc;
  }
}

// ---------------- K2: fused projection GEMM  P = emb @ [Wk;Wv;Wqf+Wql]^T ----------------
// grid (125, 6), block 256. Tile 64x64, thread 4x4, K=128 in steps of 16.
__global__ __launch_bounds__(256) void k_proj(const float* __restrict__ emb,
                                              const float* __restrict__ Wk,
                                              const float* __restrict__ Wv,
                                              const float* __restrict__ Wqf,
                                              const float* __restrict__ Wql,
                                              float* __restrict__ Karr,
                                              float* __restrict__ Varr,
                                              float* __restrict__ QFL) {
  __shared__ float Als[16][68];
  __shared__ float Bls[16][68];
  int mt = blockIdx.x, nt = blockIdx.y;
  int t = threadIdx.x;
  int ty = t >> 4, tx = t & 15;
  int row4 = t >> 2, kq = t & 3;
  float acc[4][4] = {};
  for (int k0 = 0; k0 < 128; k0 += 16) {
    const float* ap = emb + (size_t)(mt * 64 + row4) * EE + k0 + kq * 4;
    float4 av = *(const float4*)ap;
    int j = nt * 64 + row4;
    float4 bv;
    if (j < 128) {
      bv = *(const float4*)(Wk + (size_t)j * EE + k0 + kq * 4);
    } else if (j < 256) {
      bv = *(const float4*)(Wv + (size_t)(j - 128) * EE + k0 + kq * 4);
    } else {
      float4 f = *(const float4*)(Wqf + (size_t)(j - 256) * EE + k0 + kq * 4);
      float4 l = *(const float4*)(Wql + (size_t)(j - 256) * EE + k0 + kq * 4);
      bv = make_float4(f.x + l.x, f.y + l.y, f.z + l.z, f.w + l.w);
    }
    Als[kq * 4 + 0][row4] = av.x; Als[kq * 4 + 1][row4] = av.y;
    Als[kq * 4 + 2][row4] = av.z; Als[kq * 4 + 3][row4] = av.w;
    Bls[kq * 4 + 0][row4] = bv.x; Bls[kq * 4 + 1][row4] = bv.y;
    Bls[kq * 4 + 2][row4] = bv.z; Bls[kq * 4 + 3][row4] = bv.w;
    __syncthreads();
#pragma unroll
    for (int k = 0; k < 16; ++k) {
      float a0 = Als[k][ty * 4 + 0], a1 = Als[k][ty * 4 + 1];
      float a2 = Als[k][ty * 4 + 2], a3 = Als[k][ty * 4 + 3];
      float b0 = Bls[k][tx * 4 + 0], b1 = Bls[k][tx * 4 + 1];
      float b2 = Bls[k][tx * 4 + 2], b3 = Bls[k][tx * 4 + 3];
      acc[0][0] += a0 * b0; acc[0][1] += a0 * b1; acc[0][2] += a0 * b2; acc[0][3] += a0 * b3;
      acc[1][0] += a1 * b0; acc[1][1] += a1 * b1; acc[1][2] += a1 * b2; acc[1][3] += a1 * b3;
      acc[2][0] += a2 * b0; acc[2][1] += a2 * b1; acc[2][2] += a2 * b2; acc[2][3] += a2 * b3;
      acc[3][0] += a3 * b0; acc[3][1] += a3 * b1; acc[3][2] += a3 * b2; acc[3][3] += a3 * b3;
    }
    __syncthreads();
  }
  float* outp; int cb;
  if (nt < 2)      { outp = Karr; cb = nt * 64; }
  else if (nt < 4) { outp = Varr; cb = (nt - 2) * 64; }
  else             { outp = QFL;  cb = (nt - 4) * 64; }
#pragma unroll
  for (int i = 0; i < 4; ++i) {
    int r = mt * 64 + ty * 4 + i;
    float4 v = make_float4(acc[i][0], acc[i][1], acc[i][2], acc[i][3]);
    *(float4*)(outp + (size_t)r * EE + cb + tx * 4) = v;
  }
}

// ----- lex-argmin reduction steps: DPP row rotations (fast) + shfl for 16/32 -----
template <int CTRL>
__device__ __forceinline__ void red_step_dpp(float& bv, int& bn) {
  int ovi = __builtin_amdgcn_update_dpp(0, __float_as_int(bv), CTRL, 0xf, 0xf, false);
  int on  = __builtin_amdgcn_update_dpp(0, bn, CTRL, 0xf, 0xf, false);
  float ov = __int_as_float(ovi);
  bool better = (ov < bv) || (ov == bv && on < bn);
  bv = better ? ov : bv;
  bn = better ? on : bn;
}
__device__ __forceinline__ void red_step_shfl(int off, float& bv, int& bn) {
  float ov = __shfl_xor(bv, off);
  int on = __shfl_xor(bn, off);
  bool better = (ov < bv) || (ov == bv && on < bn);
  bv = better ? ov : bv;
  bn = better ? on : bn;
}

// ---------------- K3: per-(b,g) KNN + glimpse attention -> outg (B,G,128) ----------------
// one wave per (b,g); grid 2000 x 256 (4 waves/block)
__global__ __launch_bounds__(256) void k_glimpse(const int* __restrict__ last_node,
                                                 const float* __restrict__ coords,
                                                 const float* __restrict__ mask,
                                                 const float* __restrict__ qg,
                                                 const float* __restrict__ QFL,
                                                 const float* __restrict__ Karr,
                                                 const float* __restrict__ Varr,
                                                 float* __restrict__ outg) {
  __shared__ float pbuf[4][128];
  __shared__ int   nbuf[4][16];
  const float INF = __builtin_inff();
  int wv = threadIdx.x >> 6;
  int lane = threadIdx.x & 63;
  int wid = (blockIdx.x * blockDim.x + threadIdx.x) >> 6;
  int b = wid / GG, g = wid % GG;
  int last = last_node[b * GG + g];
  const float2* cb2 = (const float2*)(coords + (size_t)b * NN * 2);
  float2 lc = cb2[last];
  float lc2 = lc.x * lc.x + lc.y * lc.y;
  const float* mrow = mask + ((size_t)b * GG + g) * NN;
  // per-lane squared distances, n = lane + 64*i
  float d2v[16];
#pragma unroll
  for (int i = 0; i < 16; ++i) {
    int n = lane + 64 * i;
    float v = INF;
    if (n < NN) {
      float2 c = cb2[n];
      float d2 = lc2 + (c.x * c.x + c.y * c.y) - 2.f * (lc.x * c.x + lc.y * c.y);
      d2 = fmaxf(d2, 0.f);  // match reference sqrt(max(d2,0)) tie semantics
      if (mrow[n] == -INF) d2 = INF;
      v = d2;
    }
    d2v[i] = v;
  }
  // 16 rounds of wave lex-argmin on (d2, n); ties -> smaller n (matches lax.top_k)
  int h = lane >> 3;   // head 0..7
  int kk = lane & 7;   // this lane scores k=kk and k=kk+8
  int n0sel = 0, n1sel = 0;
  for (int s = 0; s < 16; ++s) {
    float bv = d2v[0]; int bn = lane;
#pragma unroll
    for (int i = 1; i < 16; ++i) {
      float v = d2v[i];
      bool better = (v < bv);  // same lane: larger i => larger n, strict < keeps smaller n
      bv = better ? v : bv;
      bn = better ? (lane + (i << 6)) : bn;
    }
    red_step_dpp<0x121>(bv, bn);   // ror 1 within 16-lane row
    red_step_dpp<0x122>(bv, bn);   // ror 2
    red_step_dpp<0x124>(bv, bn);   // ror 4
    red_step_dpp<0x128>(bv, bn);   // ror 8 -> full row reduced
    red_step_shfl(16, bv, bn);
    red_step_shfl(32, bv, bn);
    n0sel = (s == kk) ? bn : n0sel;
    n1sel = (s == kk + 8) ? bn : n1sel;
#pragma unroll
    for (int i = 0; i < 16; ++i)
      d2v[i] = (lane + (i << 6) == bn) ? INF : d2v[i];
  }
  // glimpse q for this lane's head (vectorized loads; accumulation order = d ascending)
  float qh[16];
  {
    const float4* qg4 = (const float4*)(qg + b * EE + h * 16);
    const float4* qf4 = (const float4*)(QFL + ((size_t)b * NN + last) * EE + h * 16);
#pragma unroll
    for (int u = 0; u < 4; ++u) {
      float4 a = qg4[u], c = qf4[u];
      qh[u * 4 + 0] = a.x + c.x; qh[u * 4 + 1] = a.y + c.y;
      qh[u * 4 + 2] = a.z + c.z; qh[u * 4 + 3] = a.w + c.w;
    }
  }
  // scores for (h, kk) and (h, kk+8)
  const float* Kb = Karr + (size_t)b * NN * EE;
  float s0 = 0.f, s1 = 0.f;
  {
    const float4* k04 = (const float4*)(Kb + (size_t)n0sel * EE + h * 16);
    const float4* k14 = (const float4*)(Kb + (size_t)n1sel * EE + h * 16);
    float4 ka[4], kb[4];
#pragma unroll
    for (int u = 0; u < 4; ++u) { ka[u] = k04[u]; kb[u] = k14[u]; }
#pragma unroll
    for (int u = 0; u < 4; ++u) {
      s0 += qh[u * 4 + 0] * ka[u].x; s0 += qh[u * 4 + 1] * ka[u].y;
      s0 += qh[u * 4 + 2] * ka[u].z; s0 += qh[u * 4 + 3] * ka[u].w;
      s1 += qh[u * 4 + 0] * kb[u].x; s1 += qh[u * 4 + 1] * kb[u].y;
      s1 += qh[u * 4 + 2] * kb[u].z; s1 += qh[u * 4 + 3] * kb[u].w;
    }
  }
  s0 *= 0.25f; s1 *= 0.25f;  // 1/sqrt(16)
  // softmax over the 16 scores of head h (2 per lane across the 8-lane group)
  float m = fmaxf(s0, s1);
#pragma unroll
  for (int off = 1; off < 8; off <<= 1) m = fmaxf(m, __shfl_xor(m, off));
  float e0 = expf(s0 - m), e1 = expf(s1 - m);
  float se = e0 + e1;
#pragma unroll
  for (int off = 1; off < 8; off <<= 1) se += __shfl_xor(se, off);
  float p0 = e0 / se, p1 = e1 / se;
  // stage probs + indices in LDS (per-wave slice; wave-coherent, no barrier needed)
  pbuf[wv][h * 16 + kk] = p0;
  pbuf[wv][h * 16 + kk + 8] = p1;
  if (h == 0) { nbuf[wv][kk] = n0sel; nbuf[wv][kk + 8] = n1sel; }
  // PV: out dims for this lane: e = h*16 + kk*2 + {0,1}
  const float* Vb = Varr + (size_t)b * NN * EE;
  float o0 = 0.f, o1 = 0.f;
#pragma unroll
  for (int c = 0; c < 2; ++c) {
    int nk[8]; float pk[8]; float2 vv[8];
#pragma unroll
    for (int j = 0; j < 8; ++j) { nk[j] = nbuf[wv][c * 8 + j]; pk[j] = pbuf[wv][h * 16 + c * 8 + j]; }
#pragma unroll
    for (int j = 0; j < 8; ++j)
      vv[j] = *(const float2*)(Vb + (size_t)nk[j] * EE + h * 16 + kk * 2);
#pragma unroll
    for (int j = 0; j < 8; ++j) { o0 += pk[j] * vv[j].x; o1 += pk[j] * vv[j].y; }
  }
  *(float2*)(outg + ((size_t)b * GG + g) * EE + h * 16 + kk * 2) = make_float2(o0, o1);
}

// ---------------- K4: final_q = outg @ W_comb^T + b_comb ----------------
// grid (125, 2), block 256
__global__ __launch_bounds__(256) void k_comb(const float* __restrict__ outg,
                                              const float* __restrict__ Wc,
                                              const float* __restrict__ bc,
                                              float* __restrict__ fq) {
  __shared__ float Als[16][68];
  __shared__ float Bls[16][68];
  int mt = blockIdx.x, nt = blockIdx.y;
  int t = threadIdx.x;
  int ty = t >> 4, tx = t & 15;
  int row4 = t >> 2, kq = t & 3;
  float acc[4][4] = {};
  for (int k0 = 0; k0 < 128; k0 += 16) {
    float4 av = *(const float4*)(outg + (size_t)(mt * 64 + row4) * EE + k0 + kq * 4);
    int j = nt * 64 + row4;
    float4 bv = *(const float4*)(Wc + (size_t)j * EE + k0 + kq * 4);
    Als[kq * 4 + 0][row4] = av.x; Als[kq * 4 + 1][row4] = av.y;
    Als[kq * 4 + 2][row4] = av.z; Als[kq * 4 + 3][row4] = av.w;
    Bls[kq * 4 + 0][row4] = bv.x; Bls[kq * 4 + 1][row4] = bv.y;
    Bls[kq * 4 + 2][row4] = bv.z; Bls[kq * 4 + 3][row4] = bv.w;
    __syncthreads();
#pragma unroll
    for (int k = 0; k < 16; ++k) {
      float a0 = Als[k][ty * 4 + 0], a1 = Als[k][ty * 4 + 1];
      float a2 = Als[k][ty * 4 + 2], a3 = Als[k][ty * 4 + 3];
      float b0 = Bls[k][tx * 4 + 0], b1 = Bls[k][tx * 4 + 1];
      float b2 = Bls[k][tx * 4 + 2], b3 = Bls[k][tx * 4 + 3];
      acc[0][0] += a0 * b0; acc[0][1] += a0 * b1; acc[0][2] += a0 * b2; acc[0][3] += a0 * b3;
      acc[1][0] += a1 * b0; acc[1][1] += a1 * b1; acc[1][2] += a1 * b2; acc[1][3] += a1 * b3;
      acc[2][0] += a2 * b0; acc[2][1] += a2 * b1; acc[2][2] += a2 * b2; acc[2][3] += a2 * b3;
      acc[3][0] += a3 * b0; acc[3][1] += a3 * b1; acc[3][2] += a3 * b2; acc[3][3] += a3 * b3;
    }
    __syncthreads();
  }
#pragma unroll
  for (int i = 0; i < 4; ++i) {
    int r = mt * 64 + ty * 4 + i;
    int c = nt * 64 + tx * 4;
    float4 v = make_float4(acc[i][0] + bc[c + 0], acc[i][1] + bc[c + 1],
                           acc[i][2] + bc[c + 2], acc[i][3] + bc[c + 3]);
    *(float4*)(fq + (size_t)r * EE + c) = v;
  }
}

// ---------------- K5: score GEMM 128x128 tile + tanh clip + exp + partial sums ----------
// grid (8, 8, 8): b, g-tile(128), n-tile(128). block 256, thread 8x8.
// exp needs no max-subtraction: logits in [-10,10] (+ -inf mask) -> overflow-safe.
__global__ __launch_bounds__(256, 2) void k_score(const float* __restrict__ fq,
                                                  const float* __restrict__ emb,
                                                  const float* __restrict__ mask,
                                                  float* __restrict__ out,
                                                  float* __restrict__ part) {
  __shared__ float As[16][132];   // row stride 528B: 16B-aligned, float4-readable
  __shared__ float Bs[16][132];
  int b = blockIdx.x, gt = blockIdx.y, nt = blockIdx.z;
  int t = threadIdx.x;
  int tx = t & 15, ty = t >> 4;
  int g0 = gt * 128, n0 = nt * 128;
  const float* A = fq + (size_t)b * GG * EE;
  const float* Bm = emb + (size_t)b * NN * EE;
  int lr = t >> 1;          // staging row 0..127
  int lq = t & 1;           // which 8-float half of the 16-wide k slab
  int ar = min(g0 + lr, GG - 1);
  int br = min(n0 + lr, NN - 1);
  const float* apos = A + (size_t)ar * EE + lq * 8;
  const float* bpos = Bm + (size_t)br * EE + lq * 8;

  float acc[8][8] = {};
  // prefetch k0 = 0
  float4 sa0 = *(const float4*)(apos + 0);
  float4 sa1 = *(const float4*)(apos + 4);
  float4 sb0 = *(const float4*)(bpos + 0);
  float4 sb1 = *(const float4*)(bpos + 4);
  for (int k0 = 0; k0 < 128; k0 += 16) {
    __syncthreads();  // previous compute done reading LDS
    As[lq * 8 + 0][lr] = sa0.x; As[lq * 8 + 1][lr] = sa0.y;
    As[lq * 8 + 2][lr] = sa0.z; As[lq * 8 + 3][lr] = sa0.w;
    As[lq * 8 + 4][lr] = sa1.x; As[lq * 8 + 5][lr] = sa1.y;
    As[lq * 8 + 6][lr] = sa1.z; As[lq * 8 + 7][lr] = sa1.w;
    Bs[lq * 8 + 0][lr] = sb0.x; Bs[lq * 8 + 1][lr] = sb0.y;
    Bs[lq * 8 + 2][lr] = sb0.z; Bs[lq * 8 + 3][lr] = sb0.w;
    Bs[lq * 8 + 4][lr] = sb1.x; Bs[lq * 8 + 5][lr] = sb1.y;
    Bs[lq * 8 + 6][lr] = sb1.z; Bs[lq * 8 + 7][lr] = sb1.w;
    __syncthreads();
    if (k0 < 112) {  // prefetch next slab (overlaps with compute below)
      sa0 = *(const float4*)(apos + k0 + 16);
      sa1 = *(const float4*)(apos + k0 + 20);
      sb0 = *(const float4*)(bpos + k0 + 16);
      sb1 = *(const float4*)(bpos + k0 + 20);
    }
#pragma unroll
    for (int k = 0; k < 16; ++k) {
      float4 av0 = *(const float4*)&As[k][ty * 8];
      float4 av1 = *(const float4*)&As[k][ty * 8 + 4];
      float4 bv0 = *(const float4*)&Bs[k][tx * 8];
      float4 bv1 = *(const float4*)&Bs[k][tx * 8 + 4];
      float af[8] = {av0.x, av0.y, av0.z, av0.w, av1.x, av1.y, av1.z, av1.w};
      float bf[8] = {bv0.x, bv0.y, bv0.z, bv0.w, bv1.x, bv1.y, bv1.z, bv1.w};
#pragma unroll
      for (int i = 0; i < 8; ++i)
#pragma unroll
        for (int j = 0; j < 8; ++j) acc[i][j] += af[i] * bf[j];
    }
  }

  const float rs = 0.08838834764831845f;  // 1/sqrt(128)
  const float NEGINF = -__builtin_inff();
  int gbase = g0 + ty * 8;
  int nb = n0 + tx * 8;
  bool nfull = (nb + 7 < NN);
#pragma unroll
  for (int i = 0; i < 8; ++i) {
    int g = gbase + i;
    int gc = g < GG ? g : GG - 1;
    const float* mrow = mask + ((size_t)b * GG + gc) * NN;
    float* orow = out + ((size_t)b * GG + gc) * NN;
    float mv[8];
    if (nfull) {
      float4 m0 = *(const float4*)(mrow + nb);
      float4 m1 = *(const float4*)(mrow + nb + 4);
      mv[0] = m0.x; mv[1] = m0.y; mv[2] = m0.z; mv[3] = m0.w;
      mv[4] = m1.x; mv[5] = m1.y; mv[6] = m1.z; mv[7] = m1.w;
    } else {
#pragma unroll
      for (int j = 0; j < 8; ++j) mv[j] = (nb + j < NN) ? mrow[nb + j] : NEGINF;
    }
    float e[8];
    float rsum = 0.f;
#pragma unroll
    for (int j = 0; j < 8; ++j) {
      float sc = acc[i][j] * rs;
      float u = __expf(2.f * sc);                          // e^{2sc}; inf-safe
      float th = 1.f - 2.f * __builtin_amdgcn_rcpf(u + 1.f);  // tanh(sc)
      float ev = __expf(10.f * th + mv[j]);                // mask -inf -> 0
      e[j] = ev;
      rsum += ev;   // OOB j contributes 0 (mv=-inf)
    }
    if (g < GG) {
      if (nfull) {
        *(float4*)(orow + nb)     = make_float4(e[0], e[1], e[2], e[3]);
        *(float4*)(orow + nb + 4) = make_float4(e[4], e[5], e[6], e[7]);
      } else {
#pragma unroll
        for (int j = 0; j < 8; ++j)
          if (nb + j < NN) orow[nb + j] = e[j];
      }
    }
#pragma unroll
    for (int off = 1; off < 16; off <<= 1) rsum += __shfl_xor(rsum, off);
    if (tx == 0 && g < GG) part[((size_t)b * GG + g) * 8 + nt] = rsum;
  }
}

// ---------------- K6: normalize: probs = exp / rowsum ----------------
// grid 8000 (one block per (b,g) row), block 256
__global__ __launch_bounds__(256) void k_norm(const float* __restrict__ part,
                                              float* __restrict__ out) {
  int row = blockIdx.x;
  __shared__ float ssum;
  int t = threadIdx.x;
  float v = (t < 8) ? part[(size_t)row * 8 + t] : 0.f;
#pragma unroll
  for (int off = 1; off < 8; off <<= 1) v += __shfl_xor(v, off);
  if (t == 0) ssum = v;
  __syncthreads();
  float inv = 1.f / ssum;
  if (t < 250) {
    float4* o = (float4*)(out + (size_t)row * NN);
    float4 x = o[t];
    x.x *= inv; x.y *= inv; x.z *= inv; x.w *= inv;
    o[t] = x;
  }
}

extern "C" void kernel_launch(void* const* d_in, const int* in_sizes, int n_in,
                              void* d_out, int out_size, void* d_ws, size_t ws_size,
                              hipStream_t stream) {
  const int*   last_node = (const int*)d_in[0];
  const float* coords    = (const float*)d_in[1];
  const float* emb       = (const float*)d_in[2];
  const float* mask      = (const float*)d_in[3];
  const float* Wqg       = (const float*)d_in[4];
  const float* Wqf       = (const float*)d_in[5];
  const float* Wql       = (const float*)d_in[6];
  const float* Wk        = (const float*)d_in[7];
  const float* Wv        = (const float*)d_in[8];
  const float* Wc        = (const float*)d_in[9];
  const float* bc        = (const float*)d_in[10];
  float* out = (float*)d_out;
  float* ws  = (float*)d_ws;

  float* qg   = ws + OFF_QG;
  float* Karr = ws + OFF_K;
  float* Varr = ws + OFF_V;
  float* QFL  = ws + OFF_QFL;
  float* outg = ws + OFF_OUTG;
  float* fq   = ws + OFF_FQ;
  float* part = ws + OFF_PART;

  k_graphq<<<dim3(BD), dim3(1024), 0, stream>>>(emb, Wqg, qg);
  k_proj<<<dim3(125, 6), dim3(256), 0, stream>>>(emb, Wk, Wv, Wqf, Wql, Karr, Varr, QFL);
  k_glimpse<<<dim3(2000), dim3(256), 0, stream>>>(last_node, coords, mask, qg, QFL, Karr, Varr, outg);
  k_comb<<<dim3(125, 2), dim3(256), 0, stream>>>(outg, Wc, bc, fq);
  k_score<<<dim3(8, 8, 8), dim3(256), 0, stream>>>(fq, emb, mask, out, part);
  k_norm<<<dim3(8000), dim3(256), 0, stream>>>(part, out);
}

// Round 6
// 214.442 us; speedup vs baseline: 1.1018x; 1.0492x over previous
//
#include <hip/hip_runtime.h>
#include <math.h>

#define BD 8
#define NN 1000
#define GG 1000
#define EE 128

typedef unsigned long long u64;

// ws layout (floats)
#define OFF_QG    0                       // B*128
#define OFF_K     1024                    // 8000*128
#define OFF_V     (OFF_K + 1024000)
#define OFF_QFL   (OFF_V + 1024000)
#define OFF_OUTG  (OFF_QFL + 1024000)
#define OFF_FQ    (OFF_OUTG + 1024000)
#define OFF_PART  (OFF_FQ + 1024000)      // 8000*8
#define OFF_GPART (OFF_PART + 64000)      // 8*25*128

// ---------------- K1a: partial row sums of embeddings (B x 25 x 128) ----------------
__global__ __launch_bounds__(256) void k_gq1(const float* __restrict__ emb,
                                             float* __restrict__ gpart) {
  __shared__ float ps[2][128];
  int b = blockIdx.x, blk = blockIdx.y;
  int t = threadIdx.x;
  int e = t & 127, p = t >> 7;  // 2 half-slices of 20 rows
  const float* eb = emb + ((size_t)b * NN + blk * 40 + p * 20) * EE + e;
  float s = 0.f;
#pragma unroll 4
  for (int n = 0; n < 20; ++n) s += eb[(size_t)n * EE];
  ps[p][e] = s;
  __syncthreads();
  if (t < 128) gpart[(b * 25 + blk) * 128 + t] = ps[0][t] + ps[1][t];
}

// ---------------- K1b: finalize mean + q_graph = mean @ Wqg^T ----------------
__global__ __launch_bounds__(128) void k_gq2(const float* __restrict__ gpart,
                                             const float* __restrict__ Wqg,
                                             float* __restrict__ qg) {
  __shared__ float ge[128];
  int b = blockIdx.x, t = threadIdx.x;
  float s = 0.f;
#pragma unroll 5
  for (int j = 0; j < 25; ++j) s += gpart[(b * 25 + j) * 128 + t];
  ge[t] = s * (1.f / 1000.f);
  __syncthreads();
  const float* wr = Wqg + (size_t)t * EE;
  float acc = 0.f;
#pragma unroll 8
  for (int k = 0; k < 128; ++k) acc += ge[k] * wr[k];
  qg[b * EE + t] = acc;
}

// ---------------- K2: fused projection GEMM  P = emb @ [Wk;Wv;Wqf+Wql]^T ----------------
// grid (125, 6), block 256. Tile 64x64, thread 4x4, K=128 in steps of 16.
__global__ __launch_bounds__(256) void k_proj(const float* __restrict__ emb,
                                              const float* __restrict__ Wk,
                                              const float* __restrict__ Wv,
                                              const float* __restrict__ Wqf,
                                              const float* __restrict__ Wql,
                                              float* __restrict__ Karr,
                                              float* __restrict__ Varr,
                                              float* __restrict__ QFL) {
  __shared__ float Als[16][68];
  __shared__ float Bls[16][68];
  int mt = blockIdx.x, nt = blockIdx.y;
  int t = threadIdx.x;
  int ty = t >> 4, tx = t & 15;
  int row4 = t >> 2, kq = t & 3;
  float acc[4][4] = {};
  for (int k0 = 0; k0 < 128; k0 += 16) {
    const float* ap = emb + (size_t)(mt * 64 + row4) * EE + k0 + kq * 4;
    float4 av = *(const float4*)ap;
    int j = nt * 64 + row4;
    float4 bv;
    if (j < 128) {
      bv = *(const float4*)(Wk + (size_t)j * EE + k0 + kq * 4);
    } else if (j < 256) {
      bv = *(const float4*)(Wv + (size_t)(j - 128) * EE + k0 + kq * 4);
    } else {
      float4 f = *(const float4*)(Wqf + (size_t)(j - 256) * EE + k0 + kq * 4);
      float4 l = *(const float4*)(Wql + (size_t)(j - 256) * EE + k0 + kq * 4);
      bv = make_float4(f.x + l.x, f.y + l.y, f.z + l.z, f.w + l.w);
    }
    Als[kq * 4 + 0][row4] = av.x; Als[kq * 4 + 1][row4] = av.y;
    Als[kq * 4 + 2][row4] = av.z; Als[kq * 4 + 3][row4] = av.w;
    Bls[kq * 4 + 0][row4] = bv.x; Bls[kq * 4 + 1][row4] = bv.y;
    Bls[kq * 4 + 2][row4] = bv.z; Bls[kq * 4 + 3][row4] = bv.w;
    __syncthreads();
#pragma unroll
    for (int k = 0; k < 16; ++k) {
      float a0 = Als[k][ty * 4 + 0], a1 = Als[k][ty * 4 + 1];
      float a2 = Als[k][ty * 4 + 2], a3 = Als[k][ty * 4 + 3];
      float b0 = Bls[k][tx * 4 + 0], b1 = Bls[k][tx * 4 + 1];
      float b2 = Bls[k][tx * 4 + 2], b3 = Bls[k][tx * 4 + 3];
      acc[0][0] += a0 * b0; acc[0][1] += a0 * b1; acc[0][2] += a0 * b2; acc[0][3] += a0 * b3;
      acc[1][0] += a1 * b0; acc[1][1] += a1 * b1; acc[1][2] += a1 * b2; acc[1][3] += a1 * b3;
      acc[2][0] += a2 * b0; acc[2][1] += a2 * b1; acc[2][2] += a2 * b2; acc[2][3] += a2 * b3;
      acc[3][0] += a3 * b0; acc[3][1] += a3 * b1; acc[3][2] += a3 * b2; acc[3][3] += a3 * b3;
    }
    __syncthreads();
  }
  float* outp; int cb;
  if (nt < 2)      { outp = Karr; cb = nt * 64; }
  else if (nt < 4) { outp = Varr; cb = (nt - 2) * 64; }
  else             { outp = QFL;  cb = (nt - 4) * 64; }
#pragma unroll
  for (int i = 0; i < 4; ++i) {
    int r = mt * 64 + ty * 4 + i;
    float4 v = make_float4(acc[i][0], acc[i][1], acc[i][2], acc[i][3]);
    *(float4*)(outp + (size_t)r * EE + cb + tx * 4) = v;
  }
}

// ----- 64-bit key helpers: lex-min of (dist_bits, n) packed as (bits<<10)|n -----
template <int CTRL>
__device__ __forceinline__ u64 dpp_mov64(u64 x) {
  int lo = __builtin_amdgcn_update_dpp(0, (int)(unsigned)(x & 0xffffffffULL), CTRL, 0xf, 0xf, false);
  int hi = __builtin_amdgcn_update_dpp(0, (int)(unsigned)(x >> 32), CTRL, 0xf, 0xf, false);
  return ((u64)(unsigned)hi << 32) | (unsigned)lo;
}
__device__ __forceinline__ u64 shfl_xor64(u64 x, int off) {
  int lo = __shfl_xor((int)(unsigned)(x & 0xffffffffULL), off);
  int hi = __shfl_xor((int)(unsigned)(x >> 32), off);
  return ((u64)(unsigned)hi << 32) | (unsigned)lo;
}
__device__ __forceinline__ u64 min64(u64 a, u64 b) { return a < b ? a : b; }

// ---------------- K3: per-(b,g) KNN + glimpse attention -> outg (B,G,128) ----------------
// one wave per (b,g); grid 2000 x 256 (4 waves/block)
__global__ __launch_bounds__(256) void k_glimpse(const int* __restrict__ last_node,
                                                 const float* __restrict__ coords,
                                                 const float* __restrict__ mask,
                                                 const float* __restrict__ qg,
                                                 const float* __restrict__ QFL,
                                                 const float* __restrict__ Karr,
                                                 const float* __restrict__ Varr,
                                                 float* __restrict__ outg) {
  __shared__ float pbuf[4][128];
  __shared__ int   nbuf[4][16];
  const float INF = __builtin_inff();
  int wv = threadIdx.x >> 6;
  int lane = threadIdx.x & 63;
  int wid = (blockIdx.x * blockDim.x + threadIdx.x) >> 6;
  int b = wid / GG, g = wid % GG;
  int last = last_node[b * GG + g];
  const float2* cb2 = (const float2*)(coords + (size_t)b * NN * 2);
  float2 lc = cb2[last];
  float lc2 = lc.x * lc.x + lc.y * lc.y;
  const float* mrow = mask + ((size_t)b * GG + g) * NN;
  // per-lane keys (dist_bits<<10)|n, n = lane + 64*i; exact lex order of (dist, n)
  u64 key[16];
#pragma unroll
  for (int i = 0; i < 16; ++i) {
    int n = lane + (i << 6);
    u64 k = ~0ULL;
    if (n < NN) {
      float2 c = cb2[n];
      float d2 = lc2 + (c.x * c.x + c.y * c.y) - 2.f * (lc.x * c.x + lc.y * c.y);
      float d = sqrtf(fmaxf(d2, 0.f));   // match reference sqrt rounding for ties
      if (mrow[n] == -INF) d = INF;
      k = ((u64)__float_as_uint(d) << 10) | (unsigned)n;
    }
    key[i] = k;
  }
  // 16 rounds of wave lex-argmin; ties -> smaller n (matches lax.top_k)
  int h = lane >> 3;   // head 0..7
  int kk = lane & 7;   // this lane scores k=kk and k=kk+8
  int n0sel = 0, n1sel = 0;
  for (int s = 0; s < 16; ++s) {
    u64 bk = key[0];
#pragma unroll
    for (int i = 1; i < 16; ++i) bk = min64(bk, key[i]);
    bk = min64(bk, dpp_mov64<0x121>(bk));   // row_ror:1 within 16-lane row
    bk = min64(bk, dpp_mov64<0x122>(bk));   // row_ror:2
    bk = min64(bk, dpp_mov64<0x124>(bk));   // row_ror:4
    bk = min64(bk, dpp_mov64<0x128>(bk));   // row_ror:8 -> row reduced
    bk = min64(bk, shfl_xor64(bk, 16));
    bk = min64(bk, shfl_xor64(bk, 32));
    int wn = (int)__builtin_amdgcn_readfirstlane((unsigned)bk & 1023u);  // scalar winner n
    n0sel = (s == kk) ? wn : n0sel;
    n1sel = (s == kk + 8) ? wn : n1sel;
    int iw = wn >> 6;           // scalar: which per-lane slot
    bool me = (lane == (wn & 63));
#pragma unroll
    for (int i = 0; i < 16; ++i)
      if (i == iw && me) key[i] = ~0ULL;   // scalar-guarded single-slot invalidate
  }
  // glimpse q for this lane's head (vectorized loads; accumulation order = d ascending)
  float qh[16];
  {
    const float4* qg4 = (const float4*)(qg + b * EE + h * 16);
    const float4* qf4 = (const float4*)(QFL + ((size_t)b * NN + last) * EE + h * 16);
#pragma unroll
    for (int u = 0; u < 4; ++u) {
      float4 a = qg4[u], c = qf4[u];
      qh[u * 4 + 0] = a.x + c.x; qh[u * 4 + 1] = a.y + c.y;
      qh[u * 4 + 2] = a.z + c.z; qh[u * 4 + 3] = a.w + c.w;
    }
  }
  // scores for (h, kk) and (h, kk+8)
  const float* Kb = Karr + (size_t)b * NN * EE;
  float s0 = 0.f, s1 = 0.f;
  {
    const float4* k04 = (const float4*)(Kb + (size_t)n0sel * EE + h * 16);
    const float4* k14 = (const float4*)(Kb + (size_t)n1sel * EE + h * 16);
    float4 ka[4], kb[4];
#pragma unroll
    for (int u = 0; u < 4; ++u) { ka[u] = k04[u]; kb[u] = k14[u]; }
#pragma unroll
    for (int u = 0; u < 4; ++u) {
      s0 += qh[u * 4 + 0] * ka[u].x; s0 += qh[u * 4 + 1] * ka[u].y;
      s0 += qh[u * 4 + 2] * ka[u].z; s0 += qh[u * 4 + 3] * ka[u].w;
      s1 += qh[u * 4 + 0] * kb[u].x; s1 += qh[u * 4 + 1] * kb[u].y;
      s1 += qh[u * 4 + 2] * kb[u].z; s1 += qh[u * 4 + 3] * kb[u].w;
    }
  }
  s0 *= 0.25f; s1 *= 0.25f;  // 1/sqrt(16)
  // softmax over the 16 scores of head h (2 per lane across the 8-lane group)
  float m = fmaxf(s0, s1);
#pragma unroll
  for (int off = 1; off < 8; off <<= 1) m = fmaxf(m, __shfl_xor(m, off));
  float e0 = __expf(s0 - m), e1 = __expf(s1 - m);
  float se = e0 + e1;
#pragma unroll
  for (int off = 1; off < 8; off <<= 1) se += __shfl_xor(se, off);
  float p0 = e0 / se, p1 = e1 / se;
  // stage probs + indices in LDS (per-wave slice; wave-coherent, no barrier needed)
  pbuf[wv][h * 16 + kk] = p0;
  pbuf[wv][h * 16 + kk + 8] = p1;
  if (h == 0) { nbuf[wv][kk] = n0sel; nbuf[wv][kk + 8] = n1sel; }
  // PV: out dims for this lane: e = h*16 + kk*2 + {0,1}
  const float* Vb = Varr + (size_t)b * NN * EE;
  float o0 = 0.f, o1 = 0.f;
#pragma unroll
  for (int c = 0; c < 2; ++c) {
    int nk[8]; float pk[8]; float2 vv[8];
#pragma unroll
    for (int j = 0; j < 8; ++j) { nk[j] = nbuf[wv][c * 8 + j]; pk[j] = pbuf[wv][h * 16 + c * 8 + j]; }
#pragma unroll
    for (int j = 0; j < 8; ++j)
      vv[j] = *(const float2*)(Vb + (size_t)nk[j] * EE + h * 16 + kk * 2);
#pragma unroll
    for (int j = 0; j < 8; ++j) { o0 += pk[j] * vv[j].x; o1 += pk[j] * vv[j].y; }
  }
  *(float2*)(outg + ((size_t)b * GG + g) * EE + h * 16 + kk * 2) = make_float2(o0, o1);
}

// ---------------- K4: final_q = outg @ W_comb^T + b_comb ----------------
// grid (125, 2), block 256
__global__ __launch_bounds__(256) void k_comb(const float* __restrict__ outg,
                                              const float* __restrict__ Wc,
                                              const float* __restrict__ bc,
                                              float* __restrict__ fq) {
  __shared__ float Als[16][68];
  __shared__ float Bls[16][68];
  int mt = blockIdx.x, nt = blockIdx.y;
  int t = threadIdx.x;
  int ty = t >> 4, tx = t & 15;
  int row4 = t >> 2, kq = t & 3;
  float acc[4][4] = {};
  for (int k0 = 0; k0 < 128; k0 += 16) {
    float4 av = *(const float4*)(outg + (size_t)(mt * 64 + row4) * EE + k0 + kq * 4);
    int j = nt * 64 + row4;
    float4 bv = *(const float4*)(Wc + (size_t)j * EE + k0 + kq * 4);
    Als[kq * 4 + 0][row4] = av.x; Als[kq * 4 + 1][row4] = av.y;
    Als[kq * 4 + 2][row4] = av.z; Als[kq * 4 + 3][row4] = av.w;
    Bls[kq * 4 + 0][row4] = bv.x; Bls[kq * 4 + 1][row4] = bv.y;
    Bls[kq * 4 + 2][row4] = bv.z; Bls[kq * 4 + 3][row4] = bv.w;
    __syncthreads();
#pragma unroll
    for (int k = 0; k < 16; ++k) {
      float a0 = Als[k][ty * 4 + 0], a1 = Als[k][ty * 4 + 1];
      float a2 = Als[k][ty * 4 + 2], a3 = Als[k][ty * 4 + 3];
      float b0 = Bls[k][tx * 4 + 0], b1 = Bls[k][tx * 4 + 1];
      float b2 = Bls[k][tx * 4 + 2], b3 = Bls[k][tx * 4 + 3];
      acc[0][0] += a0 * b0; acc[0][1] += a0 * b1; acc[0][2] += a0 * b2; acc[0][3] += a0 * b3;
      acc[1][0] += a1 * b0; acc[1][1] += a1 * b1; acc[1][2] += a1 * b2; acc[1][3] += a1 * b3;
      acc[2][0] += a2 * b0; acc[2][1] += a2 * b1; acc[2][2] += a2 * b2; acc[2][3] += a2 * b3;
      acc[3][0] += a3 * b0; acc[3][1] += a3 * b1; acc[3][2] += a3 * b2; acc[3][3] += a3 * b3;
    }
    __syncthreads();
  }
#pragma unroll
  for (int i = 0; i < 4; ++i) {
    int r = mt * 64 + ty * 4 + i;
    int c = nt * 64 + tx * 4;
    float4 v = make_float4(acc[i][0] + bc[c + 0], acc[i][1] + bc[c + 1],
                           acc[i][2] + bc[c + 2], acc[i][3] + bc[c + 3]);
    *(float4*)(fq + (size_t)r * EE + c) = v;
  }
}

// ---------------- K5: score GEMM 64x128 tile + tanh clip + exp + partial sums ----------
// grid (8 nt, 16 gt, 8 b), block 256, thread 4x8 (cols tx*4 and 64+tx*4: 2-way bank = free).
// exp needs no max-subtraction: logits in [-10,10] (+ -inf mask) -> overflow-safe.
__global__ __launch_bounds__(256, 4) void k_score(const float* __restrict__ fq,
                                                  const float* __restrict__ emb,
                                                  const float* __restrict__ mask,
                                                  float* __restrict__ out,
                                                  float* __restrict__ part) {
  __shared__ float As[16][68];
  __shared__ float Bs[16][132];
  int nt = blockIdx.x, gt = blockIdx.y, b = blockIdx.z;
  int t = threadIdx.x;
  int tx = t & 15, ty = t >> 4;
  int g0 = gt * 64, n0 = nt * 128;
  const float* A = fq + (size_t)b * GG * EE;
  const float* Bm = emb + (size_t)b * NN * EE;
  int la = t >> 2, akq = t & 3;          // A stage: row 0..63, k-quarter
  int lb = t >> 1, bkq = t & 1;          // B stage: row 0..127, k-half
  int ar = min(g0 + la, GG - 1);
  int br = min(n0 + lb, NN - 1);
  const float* apos = A + (size_t)ar * EE + akq * 4;
  const float* bpos = Bm + (size_t)br * EE + bkq * 8;

  float acc[4][8] = {};
  float4 pa  = *(const float4*)apos;
  float4 pb0 = *(const float4*)bpos;
  float4 pb1 = *(const float4*)(bpos + 4);
  for (int k0 = 0; k0 < 128; k0 += 16) {
    __syncthreads();
    As[akq * 4 + 0][la] = pa.x;  As[akq * 4 + 1][la] = pa.y;
    As[akq * 4 + 2][la] = pa.z;  As[akq * 4 + 3][la] = pa.w;
    Bs[bkq * 8 + 0][lb] = pb0.x; Bs[bkq * 8 + 1][lb] = pb0.y;
    Bs[bkq * 8 + 2][lb] = pb0.z; Bs[bkq * 8 + 3][lb] = pb0.w;
    Bs[bkq * 8 + 4][lb] = pb1.x; Bs[bkq * 8 + 5][lb] = pb1.y;
    Bs[bkq * 8 + 6][lb] = pb1.z; Bs[bkq * 8 + 7][lb] = pb1.w;
    __syncthreads();
    if (k0 < 112) {
      pa  = *(const float4*)(apos + k0 + 16);
      pb0 = *(const float4*)(bpos + k0 + 16);
      pb1 = *(const float4*)(bpos + k0 + 20);
    }
#pragma unroll
    for (int k = 0; k < 16; ++k) {
      float4 av  = *(const float4*)&As[k][ty * 4];
      float4 bv0 = *(const float4*)&Bs[k][tx * 4];
      float4 bv1 = *(const float4*)&Bs[k][64 + tx * 4];
      float af[4] = {av.x, av.y, av.z, av.w};
      float bf[8] = {bv0.x, bv0.y, bv0.z, bv0.w, bv1.x, bv1.y, bv1.z, bv1.w};
#pragma unroll
      for (int i = 0; i < 4; ++i)
#pragma unroll
        for (int j = 0; j < 8; ++j) acc[i][j] += af[i] * bf[j];
    }
  }

  const float rs = 0.08838834764831845f;  // 1/sqrt(128)
  const float NEGINF = -__builtin_inff();
  int gbase = g0 + ty * 4;
  int nb0 = n0 + tx * 4;        // always < 1000 (max 959)
  int nb1 = n0 + 64 + tx * 4;   // may exceed on last n-tile
  bool b1full = (nb1 + 3 < NN);
#pragma unroll
  for (int i = 0; i < 4; ++i) {
    int g = gbase + i;
    bool gv = (g < GG);
    int gc = gv ? g : GG - 1;
    const float* mrow = mask + ((size_t)b * GG + gc) * NN;
    float* orow = out + ((size_t)b * GG + gc) * NN;
    float rsum = 0.f;
    // group 0: cols nb0..nb0+3 (always in range)
    {
      float4 m0 = *(const float4*)(mrow + nb0);
      float mv[4] = {m0.x, m0.y, m0.z, m0.w};
      float e[4];
#pragma unroll
      for (int j = 0; j < 4; ++j) {
        float sc = acc[i][j] * rs;
        float u = __expf(2.f * sc);
        float th = 1.f - 2.f * __builtin_amdgcn_rcpf(u + 1.f);
        e[j] = __expf(10.f * th + mv[j]);
        rsum += e[j];
      }
      if (gv) *(float4*)(orow + nb0) = make_float4(e[0], e[1], e[2], e[3]);
    }
    // group 1: cols nb1..nb1+3 (guard on last tile)
    {
      float mv[4];
      if (b1full) {
        float4 m1 = *(const float4*)(mrow + nb1);
        mv[0] = m1.x; mv[1] = m1.y; mv[2] = m1.z; mv[3] = m1.w;
      } else {
#pragma unroll
        for (int j = 0; j < 4; ++j) mv[j] = (nb1 + j < NN) ? mrow[nb1 + j] : NEGINF;
      }
      float e[4];
#pragma unroll
      for (int j = 0; j < 4; ++j) {
        float sc = acc[i][4 + j] * rs;
        float u = __expf(2.f * sc);
        float th = 1.f - 2.f * __builtin_amdgcn_rcpf(u + 1.f);
        e[j] = __expf(10.f * th + mv[j]);   // OOB -> mv=-inf -> 0
        rsum += e[j];
      }
      if (gv) {
        if (b1full) {
          *(float4*)(orow + nb1) = make_float4(e[0], e[1], e[2], e[3]);
        } else {
#pragma unroll
          for (int j = 0; j < 4; ++j)
            if (nb1 + j < NN) orow[nb1 + j] = e[j];
        }
      }
    }
#pragma unroll
    for (int off = 1; off < 16; off <<= 1) rsum += __shfl_xor(rsum, off);
    if (tx == 0 && gv) part[((size_t)b * GG + g) * 8 + nt] = rsum;
  }
}

// ---------------- K6: normalize: probs = exp / rowsum ----------------
// grid 8000 (one block per (b,g) row), block 256
__global__ __launch_bounds__(256) void k_norm(const float* __restrict__ part,
                                              float* __restrict__ out) {
  int row = blockIdx.x;
  __shared__ float ssum;
  int t = threadIdx.x;
  float v = (t < 8) ? part[(size_t)row * 8 + t] : 0.f;
#pragma unroll
  for (int off = 1; off < 8; off <<= 1) v += __shfl_xor(v, off);
  if (t == 0) ssum = v;
  __syncthreads();
  float inv = 1.f / ssum;
  if (t < 250) {
    float4* o = (float4*)(out + (size_t)row * NN);
    float4 x = o[t];
    x.x *= inv; x.y *= inv; x.z *= inv; x.w *= inv;
    o[t] = x;
  }
}

extern "C" void kernel_launch(void* const* d_in, const int* in_sizes, int n_in,
                              void* d_out, int out_size, void* d_ws, size_t ws_size,
                              hipStream_t stream) {
  const int*   last_node = (const int*)d_in[0];
  const float* coords    = (const float*)d_in[1];
  const float* emb       = (const float*)d_in[2];
  const float* mask      = (const float*)d_in[3];
  const float* Wqg       = (const float*)d_in[4];
  const float* Wqf       = (const float*)d_in[5];
  const float* Wql       = (const float*)d_in[6];
  const float* Wk        = (const float*)d_in[7];
  const float* Wv        = (const float*)d_in[8];
  const float* Wc        = (const float*)d_in[9];
  const float* bc        = (const float*)d_in[10];
  float* out = (float*)d_out;
  float* ws  = (float*)d_ws;

  float* qg    = ws + OFF_QG;
  float* Karr  = ws + OFF_K;
  float* Varr  = ws + OFF_V;
  float* QFL   = ws + OFF_QFL;
  float* outg  = ws + OFF_OUTG;
  float* fq    = ws + OFF_FQ;
  float* part  = ws + OFF_PART;
  float* gpart = ws + OFF_GPART;

  k_gq1<<<dim3(BD, 25), dim3(256), 0, stream>>>(emb, gpart);
  k_gq2<<<dim3(BD), dim3(128), 0, stream>>>(gpart, Wqg, qg);
  k_proj<<<dim3(125, 6), dim3(256), 0, stream>>>(emb, Wk, Wv, Wqf, Wql, Karr, Varr, QFL);
  k_glimpse<<<dim3(2000), dim3(256), 0, stream>>>(last_node, coords, mask, qg, QFL, Karr, Varr, outg);
  k_comb<<<dim3(125, 2), dim3(256), 0, stream>>>(outg, Wc, bc, fq);
  k_score<<<dim3(8, 16, 8), dim3(256), 0, stream>>>(fq, emb, mask, out, part);
  k_norm<<<dim3(8000), dim3(256), 0, stream>>>(part, out);
}

// Round 7
// 208.391 us; speedup vs baseline: 1.1338x; 1.0290x over previous
//
#include <hip/hip_runtime.h>
#include <math.h>

#define BD 8
#define NN 1000
#define GG 1000
#define EE 128

typedef unsigned long long u64;

// ws layout (floats)
#define OFF_QG    0                       // B*128
#define OFF_K     1024                    // 8000*128
#define OFF_V     (OFF_K + 1024000)
#define OFF_QFL   (OFF_V + 1024000)
#define OFF_OUTG  (OFF_QFL + 1024000)
#define OFF_FQ    (OFF_OUTG + 1024000)
#define OFF_PART  (OFF_FQ + 1024000)      // 8000*8
#define OFF_GPART (OFF_PART + 64000)      // 8*25*128

// ---------------- K1a: partial row sums of embeddings (B x 25 x 128) ----------------
__global__ __launch_bounds__(256) void k_gq1(const float* __restrict__ emb,
                                             float* __restrict__ gpart) {
  __shared__ float ps[2][128];
  int b = blockIdx.x, blk = blockIdx.y;
  int t = threadIdx.x;
  int e = t & 127, p = t >> 7;  // 2 half-slices of 20 rows
  const float* eb = emb + ((size_t)b * NN + blk * 40 + p * 20) * EE + e;
  float s = 0.f;
#pragma unroll 4
  for (int n = 0; n < 20; ++n) s += eb[(size_t)n * EE];
  ps[p][e] = s;
  __syncthreads();
  if (t < 128) gpart[(b * 25 + blk) * 128 + t] = ps[0][t] + ps[1][t];
}

// ---------------- K1b: finalize mean + q_graph = mean @ Wqg^T ----------------
__global__ __launch_bounds__(128) void k_gq2(const float* __restrict__ gpart,
                                             const float* __restrict__ Wqg,
                                             float* __restrict__ qg) {
  __shared__ float ge[128];
  int b = blockIdx.x, t = threadIdx.x;
  float s = 0.f;
#pragma unroll 5
  for (int j = 0; j < 25; ++j) s += gpart[(b * 25 + j) * 128 + t];
  ge[t] = s * (1.f / 1000.f);
  __syncthreads();
  const float* wr = Wqg + (size_t)t * EE;
  float acc = 0.f;
#pragma unroll 8
  for (int k = 0; k < 128; ++k) acc += ge[k] * wr[k];
  qg[b * EE + t] = acc;
}

// ---------------- K2: fused projection GEMM  P = emb @ [Wk;Wv;Wqf+Wql]^T ----------------
// grid (125, 6), block 256. Tile 64x64, thread 4x4, K=128 in steps of 16.
__global__ __launch_bounds__(256) void k_proj(const float* __restrict__ emb,
                                              const float* __restrict__ Wk,
                                              const float* __restrict__ Wv,
                                              const float* __restrict__ Wqf,
                                              const float* __restrict__ Wql,
                                              float* __restrict__ Karr,
                                              float* __restrict__ Varr,
                                              float* __restrict__ QFL) {
  __shared__ float Als[16][68];
  __shared__ float Bls[16][68];
  int mt = blockIdx.x, nt = blockIdx.y;
  int t = threadIdx.x;
  int ty = t >> 4, tx = t & 15;
  int row4 = t >> 2, kq = t & 3;
  float acc[4][4] = {};
  for (int k0 = 0; k0 < 128; k0 += 16) {
    const float* ap = emb + (size_t)(mt * 64 + row4) * EE + k0 + kq * 4;
    float4 av = *(const float4*)ap;
    int j = nt * 64 + row4;
    float4 bv;
    if (j < 128) {
      bv = *(const float4*)(Wk + (size_t)j * EE + k0 + kq * 4);
    } else if (j < 256) {
      bv = *(const float4*)(Wv + (size_t)(j - 128) * EE + k0 + kq * 4);
    } else {
      float4 f = *(const float4*)(Wqf + (size_t)(j - 256) * EE + k0 + kq * 4);
      float4 l = *(const float4*)(Wql + (size_t)(j - 256) * EE + k0 + kq * 4);
      bv = make_float4(f.x + l.x, f.y + l.y, f.z + l.z, f.w + l.w);
    }
    Als[kq * 4 + 0][row4] = av.x; Als[kq * 4 + 1][row4] = av.y;
    Als[kq * 4 + 2][row4] = av.z; Als[kq * 4 + 3][row4] = av.w;
    Bls[kq * 4 + 0][row4] = bv.x; Bls[kq * 4 + 1][row4] = bv.y;
    Bls[kq * 4 + 2][row4] = bv.z; Bls[kq * 4 + 3][row4] = bv.w;
    __syncthreads();
#pragma unroll
    for (int k = 0; k < 16; ++k) {
      float a0 = Als[k][ty * 4 + 0], a1 = Als[k][ty * 4 + 1];
      float a2 = Als[k][ty * 4 + 2], a3 = Als[k][ty * 4 + 3];
      float b0 = Bls[k][tx * 4 + 0], b1 = Bls[k][tx * 4 + 1];
      float b2 = Bls[k][tx * 4 + 2], b3 = Bls[k][tx * 4 + 3];
      acc[0][0] += a0 * b0; acc[0][1] += a0 * b1; acc[0][2] += a0 * b2; acc[0][3] += a0 * b3;
      acc[1][0] += a1 * b0; acc[1][1] += a1 * b1; acc[1][2] += a1 * b2; acc[1][3] += a1 * b3;
      acc[2][0] += a2 * b0; acc[2][1] += a2 * b1; acc[2][2] += a2 * b2; acc[2][3] += a2 * b3;
      acc[3][0] += a3 * b0; acc[3][1] += a3 * b1; acc[3][2] += a3 * b2; acc[3][3] += a3 * b3;
    }
    __syncthreads();
  }
  float* outp; int cb;
  if (nt < 2)      { outp = Karr; cb = nt * 64; }
  else if (nt < 4) { outp = Varr; cb = (nt - 2) * 64; }
  else             { outp = QFL;  cb = (nt - 4) * 64; }
#pragma unroll
  for (int i = 0; i < 4; ++i) {
    int r = mt * 64 + ty * 4 + i;
    float4 v = make_float4(acc[i][0], acc[i][1], acc[i][2], acc[i][3]);
    *(float4*)(outp + (size_t)r * EE + cb + tx * 4) = v;
  }
}

// ----- u32 wave-min helpers (DPP row rotations + shfl for 16/32) -----
template <int CTRL>
__device__ __forceinline__ unsigned dpp_minu(unsigned x) {
  unsigned o = (unsigned)__builtin_amdgcn_update_dpp(0, (int)x, CTRL, 0xf, 0xf, false);
  return o < x ? o : x;
}
__device__ __forceinline__ unsigned wave_min_u32(unsigned x) {
  x = dpp_minu<0x121>(x);   // row_ror:1
  x = dpp_minu<0x122>(x);   // row_ror:2
  x = dpp_minu<0x124>(x);   // row_ror:4
  x = dpp_minu<0x128>(x);   // row_ror:8 -> 16-lane row reduced
  unsigned o = (unsigned)__shfl_xor((int)x, 16); x = o < x ? o : x;
  o = (unsigned)__shfl_xor((int)x, 32); x = o < x ? o : x;
  return x;
}

// ---------------- K3: per-(b,g) KNN + glimpse attention -> outg (B,G,128) ----------------
// one wave per (b,g); grid 2000 x 256 (4 waves/block)
// Selection in u32 bit-space: d2 >= 0 so IEEE bits are order-monotone as u32.
// masked nodes -> 0x7F800000 (inf, selectable, index-ordered via tie fallback);
// picked/OOB slots -> 0xFFFFFFFF (never re-picked, never beat a masked node).
__global__ __launch_bounds__(256) void k_glimpse(const int* __restrict__ last_node,
                                                 const float* __restrict__ coords,
                                                 const float* __restrict__ mask,
                                                 const float* __restrict__ qg,
                                                 const float* __restrict__ QFL,
                                                 const float* __restrict__ Karr,
                                                 const float* __restrict__ Varr,
                                                 float* __restrict__ outg) {
  __shared__ float pbuf[4][128];
  __shared__ int   nbuf[4][16];
  const float INF = __builtin_inff();
  int wv = threadIdx.x >> 6;
  int lane = threadIdx.x & 63;
  int wid = (blockIdx.x * blockDim.x + threadIdx.x) >> 6;
  int b = wid / GG, g = wid % GG;
  int last = last_node[b * GG + g];
  const float2* cb2 = (const float2*)(coords + (size_t)b * NN * 2);
  float2 lc = cb2[last];
  float lc2 = lc.x * lc.x + lc.y * lc.y;
  const float* mrow = mask + ((size_t)b * GG + g) * NN;
  // per-lane u32 keys, n = lane + 64*i
  unsigned d2u[16];
#pragma unroll
  for (int i = 0; i < 16; ++i) {
    int n = lane + (i << 6);
    unsigned k = 0xFFFFFFFFu;
    if (n < NN) {
      float2 c = cb2[n];
      float d2 = lc2 + (c.x * c.x + c.y * c.y) - 2.f * (lc.x * c.x + lc.y * c.y);
      d2 = fmaxf(d2, 0.f);
      k = __float_as_uint(d2);
      if (mrow[n] == -INF) k = 0x7F800000u;
    }
    d2u[i] = k;
  }
  // 16 rounds of wave argmin on (d2_bits, n) lex; ties -> smaller n (matches lax.top_k)
  int h = lane >> 3;   // head 0..7
  int kk = lane & 7;   // this lane scores k=kk and k=kk+8
  int n0sel = 0, n1sel = 0;
  for (int s = 0; s < 16; ++s) {
    // per-lane scan: first (lowest-slot) min  -> lowest n within lane
    unsigned bv = d2u[0]; int bs = 0;
#pragma unroll
    for (int i = 1; i < 16; ++i) {
      bool better = d2u[i] < bv;
      bv = better ? d2u[i] : bv;
      bs = better ? i : bs;
    }
    unsigned wm = wave_min_u32(bv);
    u64 tied = __ballot(bv == wm);
    int wn;
    if (__popcll(tied) == 1) {
      int wl = (int)__builtin_ctzll(tied);              // unique winner lane (scalar)
      int ws = __builtin_amdgcn_readlane(bs, wl);       // its slot
      wn = wl + (ws << 6);
    } else {
      // exact tie on value: min n among tied lanes
      unsigned cn = (bv == wm) ? (unsigned)(lane + (bs << 6)) : 0x7FFFFFFFu;
      cn = wave_min_u32(cn);
      wn = (int)__builtin_amdgcn_readfirstlane((int)cn);
    }
    n0sel = (s == kk) ? wn : n0sel;
    n1sel = (s == kk + 8) ? wn : n1sel;
    int iw = wn >> 6;                 // scalar slot of winner
    bool me = (lane == (wn & 63));
#pragma unroll
    for (int i = 0; i < 16; ++i)
      if (i == iw && me) d2u[i] = 0xFFFFFFFFu;   // scalar-guarded single-slot invalidate
  }
  // glimpse q for this lane's head (vectorized loads; accumulation order = d ascending)
  float qh[16];
  {
    const float4* qg4 = (const float4*)(qg + b * EE + h * 16);
    const float4* qf4 = (const float4*)(QFL + ((size_t)b * NN + last) * EE + h * 16);
#pragma unroll
    for (int u = 0; u < 4; ++u) {
      float4 a = qg4[u], c = qf4[u];
      qh[u * 4 + 0] = a.x + c.x; qh[u * 4 + 1] = a.y + c.y;
      qh[u * 4 + 2] = a.z + c.z; qh[u * 4 + 3] = a.w + c.w;
    }
  }
  // scores for (h, kk) and (h, kk+8)
  const float* Kb = Karr + (size_t)b * NN * EE;
  float s0 = 0.f, s1 = 0.f;
  {
    const float4* k04 = (const float4*)(Kb + (size_t)n0sel * EE + h * 16);
    const float4* k14 = (const float4*)(Kb + (size_t)n1sel * EE + h * 16);
    float4 ka[4], kb[4];
#pragma unroll
    for (int u = 0; u < 4; ++u) { ka[u] = k04[u]; kb[u] = k14[u]; }
#pragma unroll
    for (int u = 0; u < 4; ++u) {
      s0 += qh[u * 4 + 0] * ka[u].x; s0 += qh[u * 4 + 1] * ka[u].y;
      s0 += qh[u * 4 + 2] * ka[u].z; s0 += qh[u * 4 + 3] * ka[u].w;
      s1 += qh[u * 4 + 0] * kb[u].x; s1 += qh[u * 4 + 1] * kb[u].y;
      s1 += qh[u * 4 + 2] * kb[u].z; s1 += qh[u * 4 + 3] * kb[u].w;
    }
  }
  s0 *= 0.25f; s1 *= 0.25f;  // 1/sqrt(16)
  // softmax over the 16 scores of head h (2 per lane across the 8-lane group)
  float m = fmaxf(s0, s1);
#pragma unroll
  for (int off = 1; off < 8; off <<= 1) m = fmaxf(m, __shfl_xor(m, off));
  float e0 = __expf(s0 - m), e1 = __expf(s1 - m);
  float se = e0 + e1;
#pragma unroll
  for (int off = 1; off < 8; off <<= 1) se += __shfl_xor(se, off);
  float p0 = e0 / se, p1 = e1 / se;
  // stage probs + indices in LDS (per-wave slice; wave-coherent, no barrier needed)
  pbuf[wv][h * 16 + kk] = p0;
  pbuf[wv][h * 16 + kk + 8] = p1;
  if (h == 0) { nbuf[wv][kk] = n0sel; nbuf[wv][kk + 8] = n1sel; }
  // PV: out dims for this lane: e = h*16 + kk*2 + {0,1}
  const float* Vb = Varr + (size_t)b * NN * EE;
  float o0 = 0.f, o1 = 0.f;
#pragma unroll
  for (int c = 0; c < 2; ++c) {
    int nk[8]; float pk[8]; float2 vv[8];
#pragma unroll
    for (int j = 0; j < 8; ++j) { nk[j] = nbuf[wv][c * 8 + j]; pk[j] = pbuf[wv][h * 16 + c * 8 + j]; }
#pragma unroll
    for (int j = 0; j < 8; ++j)
      vv[j] = *(const float2*)(Vb + (size_t)nk[j] * EE + h * 16 + kk * 2);
#pragma unroll
    for (int j = 0; j < 8; ++j) { o0 += pk[j] * vv[j].x; o1 += pk[j] * vv[j].y; }
  }
  *(float2*)(outg + ((size_t)b * GG + g) * EE + h * 16 + kk * 2) = make_float2(o0, o1);
}

// ---------------- K4: final_q = outg @ W_comb^T + b_comb ----------------
// grid (125, 2), block 256
__global__ __launch_bounds__(256) void k_comb(const float* __restrict__ outg,
                                              const float* __restrict__ Wc,
                                              const float* __restrict__ bc,
                                              float* __restrict__ fq) {
  __shared__ float Als[16][68];
  __shared__ float Bls[16][68];
  int mt = blockIdx.x, nt = blockIdx.y;
  int t = threadIdx.x;
  int ty = t >> 4, tx = t & 15;
  int row4 = t >> 2, kq = t & 3;
  float acc[4][4] = {};
  for (int k0 = 0; k0 < 128; k0 += 16) {
    float4 av = *(const float4*)(outg + (size_t)(mt * 64 + row4) * EE + k0 + kq * 4);
    int j = nt * 64 + row4;
    float4 bv = *(const float4*)(Wc + (size_t)j * EE + k0 + kq * 4);
    Als[kq * 4 + 0][row4] = av.x; Als[kq * 4 + 1][row4] = av.y;
    Als[kq * 4 + 2][row4] = av.z; Als[kq * 4 + 3][row4] = av.w;
    Bls[kq * 4 + 0][row4] = bv.x; Bls[kq * 4 + 1][row4] = bv.y;
    Bls[kq * 4 + 2][row4] = bv.z; Bls[kq * 4 + 3][row4] = bv.w;
    __syncthreads();
#pragma unroll
    for (int k = 0; k < 16; ++k) {
      float a0 = Als[k][ty * 4 + 0], a1 = Als[k][ty * 4 + 1];
      float a2 = Als[k][ty * 4 + 2], a3 = Als[k][ty * 4 + 3];
      float b0 = Bls[k][tx * 4 + 0], b1 = Bls[k][tx * 4 + 1];
      float b2 = Bls[k][tx * 4 + 2], b3 = Bls[k][tx * 4 + 3];
      acc[0][0] += a0 * b0; acc[0][1] += a0 * b1; acc[0][2] += a0 * b2; acc[0][3] += a0 * b3;
      acc[1][0] += a1 * b0; acc[1][1] += a1 * b1; acc[1][2] += a1 * b2; acc[1][3] += a1 * b3;
      acc[2][0] += a2 * b0; acc[2][1] += a2 * b1; acc[2][2] += a2 * b2; acc[2][3] += a2 * b3;
      acc[3][0] += a3 * b0; acc[3][1] += a3 * b1; acc[3][2] += a3 * b2; acc[3][3] += a3 * b3;
    }
    __syncthreads();
  }
#pragma unroll
  for (int i = 0; i < 4; ++i) {
    int r = mt * 64 + ty * 4 + i;
    int c = nt * 64 + tx * 4;
    float4 v = make_float4(acc[i][0] + bc[c + 0], acc[i][1] + bc[c + 1],
                           acc[i][2] + bc[c + 2], acc[i][3] + bc[c + 3]);
    *(float4*)(fq + (size_t)r * EE + c) = v;
  }
}

// ---------------- K5: score GEMM 64x128 tile + tanh clip + exp + partial sums ----------
// grid (8 nt, 16 gt, 8 b), block 256, thread 4x8 (cols tx*4 and 64+tx*4: 2-way bank = free).
// exp needs no max-subtraction: logits in [-10,10] (+ -inf mask) -> overflow-safe.
__global__ __launch_bounds__(256, 4) void k_score(const float* __restrict__ fq,
                                                  const float* __restrict__ emb,
                                                  const float* __restrict__ mask,
                                                  float* __restrict__ out,
                                                  float* __restrict__ part) {
  __shared__ float As[16][68];
  __shared__ float Bs[16][132];
  int nt = blockIdx.x, gt = blockIdx.y, b = blockIdx.z;
  int t = threadIdx.x;
  int tx = t & 15, ty = t >> 4;
  int g0 = gt * 64, n0 = nt * 128;
  const float* A = fq + (size_t)b * GG * EE;
  const float* Bm = emb + (size_t)b * NN * EE;
  int la = t >> 2, akq = t & 3;          // A stage: row 0..63, k-quarter
  int lb = t >> 1, bkq = t & 1;          // B stage: row 0..127, k-half
  int ar = min(g0 + la, GG - 1);
  int br = min(n0 + lb, NN - 1);
  const float* apos = A + (size_t)ar * EE + akq * 4;
  const float* bpos = Bm + (size_t)br * EE + bkq * 8;

  float acc[4][8] = {};
  float4 pa  = *(const float4*)apos;
  float4 pb0 = *(const float4*)bpos;
  float4 pb1 = *(const float4*)(bpos + 4);
  for (int k0 = 0; k0 < 128; k0 += 16) {
    __syncthreads();
    As[akq * 4 + 0][la] = pa.x;  As[akq * 4 + 1][la] = pa.y;
    As[akq * 4 + 2][la] = pa.z;  As[akq * 4 + 3][la] = pa.w;
    Bs[bkq * 8 + 0][lb] = pb0.x; Bs[bkq * 8 + 1][lb] = pb0.y;
    Bs[bkq * 8 + 2][lb] = pb0.z; Bs[bkq * 8 + 3][lb] = pb0.w;
    Bs[bkq * 8 + 4][lb] = pb1.x; Bs[bkq * 8 + 5][lb] = pb1.y;
    Bs[bkq * 8 + 6][lb] = pb1.z; Bs[bkq * 8 + 7][lb] = pb1.w;
    __syncthreads();
    if (k0 < 112) {
      pa  = *(const float4*)(apos + k0 + 16);
      pb0 = *(const float4*)(bpos + k0 + 16);
      pb1 = *(const float4*)(bpos + k0 + 20);
    }
#pragma unroll
    for (int k = 0; k < 16; ++k) {
      float4 av  = *(const float4*)&As[k][ty * 4];
      float4 bv0 = *(const float4*)&Bs[k][tx * 4];
      float4 bv1 = *(const float4*)&Bs[k][64 + tx * 4];
      float af[4] = {av.x, av.y, av.z, av.w};
      float bf[8] = {bv0.x, bv0.y, bv0.z, bv0.w, bv1.x, bv1.y, bv1.z, bv1.w};
#pragma unroll
      for (int i = 0; i < 4; ++i)
#pragma unroll
        for (int j = 0; j < 8; ++j) acc[i][j] += af[i] * bf[j];
    }
  }

  const float rs = 0.08838834764831845f;  // 1/sqrt(128)
  const float NEGINF = -__builtin_inff();
  int gbase = g0 + ty * 4;
  int nb0 = n0 + tx * 4;        // always < 1000 (max 959)
  int nb1 = n0 + 64 + tx * 4;   // may exceed on last n-tile
  bool b1full = (nb1 + 3 < NN);
#pragma unroll
  for (int i = 0; i < 4; ++i) {
    int g = gbase + i;
    bool gv = (g < GG);
    int gc = gv ? g : GG - 1;
    const float* mrow = mask + ((size_t)b * GG + gc) * NN;
    float* orow = out + ((size_t)b * GG + gc) * NN;
    float rsum = 0.f;
    // group 0: cols nb0..nb0+3 (always in range)
    {
      float4 m0 = *(const float4*)(mrow + nb0);
      float mv[4] = {m0.x, m0.y, m0.z, m0.w};
      float e[4];
#pragma unroll
      for (int j = 0; j < 4; ++j) {
        float sc = acc[i][j] * rs;
        float u = __expf(2.f * sc);
        float th = 1.f - 2.f * __builtin_amdgcn_rcpf(u + 1.f);
        e[j] = __expf(10.f * th + mv[j]);
        rsum += e[j];
      }
      if (gv) *(float4*)(orow + nb0) = make_float4(e[0], e[1], e[2], e[3]);
    }
    // group 1: cols nb1..nb1+3 (guard on last tile)
    {
      float mv[4];
      if (b1full) {
        float4 m1 = *(const float4*)(mrow + nb1);
        mv[0] = m1.x; mv[1] = m1.y; mv[2] = m1.z; mv[3] = m1.w;
      } else {
#pragma unroll
        for (int j = 0; j < 4; ++j) mv[j] = (nb1 + j < NN) ? mrow[nb1 + j] : NEGINF;
      }
      float e[4];
#pragma unroll
      for (int j = 0; j < 4; ++j) {
        float sc = acc[i][4 + j] * rs;
        float u = __expf(2.f * sc);
        float th = 1.f - 2.f * __builtin_amdgcn_rcpf(u + 1.f);
        e[j] = __expf(10.f * th + mv[j]);   // OOB -> mv=-inf -> 0
        rsum += e[j];
      }
      if (gv) {
        if (b1full) {
          *(float4*)(orow + nb1) = make_float4(e[0], e[1], e[2], e[3]);
        } else {
#pragma unroll
          for (int j = 0; j < 4; ++j)
            if (nb1 + j < NN) orow[nb1 + j] = e[j];
        }
      }
    }
#pragma unroll
    for (int off = 1; off < 16; off <<= 1) rsum += __shfl_xor(rsum, off);
    if (tx == 0 && gv) part[((size_t)b * GG + g) * 8 + nt] = rsum;
  }
}

// ---------------- K6: normalize: probs = exp / rowsum ----------------
// grid 8000 (one block per (b,g) row), block 256
__global__ __launch_bounds__(256) void k_norm(const float* __restrict__ part,
                                              float* __restrict__ out) {
  int row = blockIdx.x;
  __shared__ float ssum;
  int t = threadIdx.x;
  float v = (t < 8) ? part[(size_t)row * 8 + t] : 0.f;
#pragma unroll
  for (int off = 1; off < 8; off <<= 1) v += __shfl_xor(v, off);
  if (t == 0) ssum = v;
  __syncthreads();
  float inv = 1.f / ssum;
  if (t < 250) {
    float4* o = (float4*)(out + (size_t)row * NN);
    float4 x = o[t];
    x.x *= inv; x.y *= inv; x.z *= inv; x.w *= inv;
    o[t] = x;
  }
}

extern "C" void kernel_launch(void* const* d_in, const int* in_sizes, int n_in,
                              void* d_out, int out_size, void* d_ws, size_t ws_size,
                              hipStream_t stream) {
  const int*   last_node = (const int*)d_in[0];
  const float* coords    = (const float*)d_in[1];
  const float* emb       = (const float*)d_in[2];
  const float* mask      = (const float*)d_in[3];
  const float* Wqg       = (const float*)d_in[4];
  const float* Wqf       = (const float*)d_in[5];
  const float* Wql       = (const float*)d_in[6];
  const float* Wk        = (const float*)d_in[7];
  const float* Wv        = (const float*)d_in[8];
  const float* Wc        = (const float*)d_in[9];
  const float* bc        = (const float*)d_in[10];
  float* out = (float*)d_out;
  float* ws  = (float*)d_ws;

  float* qg    = ws + OFF_QG;
  float* Karr  = ws + OFF_K;
  float* Varr  = ws + OFF_V;
  float* QFL   = ws + OFF_QFL;
  float* outg  = ws + OFF_OUTG;
  float* fq    = ws + OFF_FQ;
  float* part  = ws + OFF_PART;
  float* gpart = ws + OFF_GPART;

  k_gq1<<<dim3(BD, 25), dim3(256), 0, stream>>>(emb, gpart);
  k_gq2<<<dim3(BD), dim3(128), 0, stream>>>(gpart, Wqg, qg);
  k_proj<<<dim3(125, 6), dim3(256), 0, stream>>>(emb, Wk, Wv, Wqf, Wql, Karr, Varr, QFL);
  k_glimpse<<<dim3(2000), dim3(256), 0, stream>>>(last_node, coords, mask, qg, QFL, Karr, Varr, outg);
  k_comb<<<dim3(125, 2), dim3(256), 0, stream>>>(outg, Wc, bc, fq);
  k_score<<<dim3(8, 16, 8), dim3(256), 0, stream>>>(fq, emb, mask, out, part);
  k_norm<<<dim3(8000), dim3(256), 0, stream>>>(part, out);
}